// Round 10
// baseline (354.528 us; speedup 1.0000x reference)
//
#include <hip/hip_runtime.h>
#include <hip/hip_fp16.h>
#include <math.h>

#define NN 100000
#define NE 1200000
#define INC 128
#define HIDC 64
#define EPSV 1e-5f
#define NPB 1024                               // nodes per bucket
#define NBUCK ((NN + NPB - 1) / NPB)           // 98
#define CHUNK 8192                             // edges per partA/hist block

typedef float f4 __attribute__((ext_vector_type(4)));
typedef _Float16 hf;
typedef _Float16 h4 __attribute__((ext_vector_type(4)));
typedef _Float16 h8 __attribute__((ext_vector_type(8)));
typedef unsigned long long u64;

// ---- bucket histogram + (block 0) weight-transpose prep ----
__global__ __launch_bounds__(256) void k_histprep(
    const int* __restrict__ dst, int* bucketTotal,
    const float* __restrict__ W1, const float* __restrict__ W2,
    hf* __restrict__ w1t, hf* __restrict__ w2t) {
    __shared__ int hist[NBUCK];
    int t = threadIdx.x;
    if (blockIdx.x == 0) {
        for (int i = t; i < 64 * 128; i += 256) {
            int c = i >> 7, k = i & 127;
            w1t[i] = (hf)W1[k * 64 + c];
        }
        for (int i = t; i < 64 * 64; i += 256) {
            int c = i >> 6, k = i & 63;
            w2t[i] = (hf)W2[k * 64 + c];
        }
    }
    if (t < NBUCK) hist[t] = 0;
    __syncthreads();
    int e0 = blockIdx.x * CHUNK;
#pragma unroll
    for (int j = 0; j < CHUNK / 256; ++j) {
        int e = e0 + j * 256 + t;
        if (e < NE) atomicAdd(&hist[dst[e] >> 10], 1);
    }
    __syncthreads();
    if (t < NBUCK && hist[t]) atomicAdd(&bucketTotal[t], hist[t]);
}

// ---- scan bucket totals ----
__global__ void k_bscan(const int* __restrict__ bucketTotal,
                        int* bucketStart, int* bucketCur, int* cursor) {
    __shared__ int s[NBUCK];
    int t = threadIdx.x;
    if (t < NBUCK) s[t] = bucketTotal[t];
    __syncthreads();
    if (t == 0) {
        int acc = 0;
        for (int i = 0; i < NBUCK; ++i) { int v = s[i]; s[i] = acc; acc += v; }
    }
    __syncthreads();
    if (t < NBUCK) { bucketStart[t] = s[t]; bucketCur[t] = s[t]; }
    if (t == 0) { bucketStart[NBUCK] = NE; cursor[NN] = NE; }
}

// ---- pass A: partition (src,dst) pairs into bucket regions ----
__global__ __launch_bounds__(256) void k_partA(
    const int* __restrict__ src, const int* __restrict__ dst,
    int* bucketCur, u64* __restrict__ pairs) {
    __shared__ int hist[NBUCK], base[NBUCK];
    int t = threadIdx.x;
    if (t < NBUCK) hist[t] = 0;
    __syncthreads();
    int e0 = blockIdx.x * CHUNK;
    int dloc[32];
#pragma unroll
    for (int j = 0; j < 32; ++j) {
        int e = e0 + j * 256 + t;
        int d = (e < NE) ? dst[e] : -1;
        dloc[j] = d;
        if (d >= 0) atomicAdd(&hist[d >> 10], 1);
    }
    __syncthreads();
    if (t < NBUCK) base[t] = atomicAdd(&bucketCur[t], hist[t]);
    __syncthreads();
    if (t < NBUCK) hist[t] = 0;
    __syncthreads();
#pragma unroll
    for (int j = 0; j < 32; ++j) {
        int e = e0 + j * 256 + t;
        int d = dloc[j];
        if (d >= 0) {
            int b = d >> 10;
            int pos = base[b] + atomicAdd(&hist[b], 1);
            pairs[pos] = ((u64)(unsigned)d << 32) | (unsigned)src[e];
        }
    }
}

// ---- pass B: per-bucket counts -> cursor/dinv; local scatter ----
__global__ __launch_bounds__(256) void k_partB(
    const int* __restrict__ bucketStart, const u64* __restrict__ pairs,
    int* __restrict__ srcSorted, int* __restrict__ cursor, float* __restrict__ dinv) {
    __shared__ int cnt1024[NPB];
    __shared__ int off1024[NPB];
    __shared__ int part[256];
    int b = blockIdx.x, t = threadIdx.x;
    int nbase = b * NPB;
    int beg = bucketStart[b], end = bucketStart[b + 1];
    for (int i = t; i < NPB; i += 256) cnt1024[i] = 0;
    __syncthreads();
    for (int i = beg + t; i < end; i += 256)
        atomicAdd(&cnt1024[(int)(pairs[i] >> 32) - nbase], 1);
    __syncthreads();
    int c[4]; int s = 0;
#pragma unroll
    for (int j = 0; j < 4; ++j) { c[j] = cnt1024[t * 4 + j]; s += c[j]; }
    part[t] = s;
    __syncthreads();
    for (int off = 1; off < 256; off <<= 1) {
        int x = (t >= off) ? part[t - off] : 0;
        __syncthreads();
        part[t] += x;
        __syncthreads();
    }
    int run = part[t] - s;
#pragma unroll
    for (int j = 0; j < 4; ++j) {
        int node = nbase + t * 4 + j;
        if (node < NN) {
            cursor[node] = beg + run;
            off1024[t * 4 + j] = run;
            dinv[node] = rsqrtf((float)c[j] + 1.0f);
            run += c[j];
        }
    }
    __syncthreads();
    for (int i = beg + t; i < end; i += 256) {
        u64 p = pairs[i];
        int d = (int)(p >> 32);
        int pos = beg + atomicAdd(&off1024[d - nbase], 1);
        srcSorted[pos] = (int)(p & 0xffffffffu);
    }
}

// ---------------- layer-1 GEMM via MFMA ----------------
__global__ __launch_bounds__(256) void k_gemm1(
    const float* __restrict__ x, const hf* __restrict__ w1t,
    const float* __restrict__ dinv, hf* __restrict__ hp) {
    int wv = threadIdx.x >> 6, l = threadIdx.x & 63;
    int r16 = l & 15, kg = l >> 4;
    int nodeBase = blockIdx.x * 64;
    int row = nodeBase + wv * 16 + r16;
    int rowC = row < NN ? row : NN - 1;
    const float* xr = x + (size_t)rowC * INC + kg * 8;
    f4 acc[4] = {{0.f,0.f,0.f,0.f},{0.f,0.f,0.f,0.f},{0.f,0.f,0.f,0.f},{0.f,0.f,0.f,0.f}};
#pragma unroll
    for (int ks = 0; ks < 4; ++ks) {
        f4 alo = *(const f4*)(xr + ks * 32);
        f4 ahi = *(const f4*)(xr + ks * 32 + 4);
        h8 a;
#pragma unroll
        for (int j = 0; j < 4; ++j) { a[j] = (hf)alo[j]; a[4 + j] = (hf)ahi[j]; }
#pragma unroll
        for (int n = 0; n < 4; ++n) {
            h8 b = *(const h8*)(w1t + (n * 16 + r16) * INC + ks * 32 + kg * 8);
            acc[n] = __builtin_amdgcn_mfma_f32_16x16x32_f16(a, b, acc[n], 0, 0, 0);
        }
    }
#pragma unroll
    for (int j = 0; j < 4; ++j) {
        int nrow = nodeBase + wv * 16 + kg * 4 + j;
        if (nrow < NN) {
            float dv = dinv[nrow];
            size_t o = (size_t)nrow * HIDC + r16;
#pragma unroll
            for (int n = 0; n < 4; ++n)
                hp[o + n * 16] = (hf)(acc[n][j] * dv);
        }
    }
}

// ---------------- layer-2 GEMM via MFMA, BN+ReLU fused ----------------
__global__ __launch_bounds__(256) void k_gemm2(
    const hf* __restrict__ agg, const hf* __restrict__ w2t,
    const float* __restrict__ scale, const float* __restrict__ shift,
    const float* __restrict__ dinv, hf* __restrict__ hp) {
    int wv = threadIdx.x >> 6, l = threadIdx.x & 63;
    int r16 = l & 15, kg = l >> 4;
    int nodeBase = blockIdx.x * 64;
    int row = nodeBase + wv * 16 + r16;
    int rowC = row < NN ? row : NN - 1;
    const hf* ar = agg + (size_t)rowC * HIDC + kg * 8;
    f4 acc[4] = {{0.f,0.f,0.f,0.f},{0.f,0.f,0.f,0.f},{0.f,0.f,0.f,0.f},{0.f,0.f,0.f,0.f}};
#pragma unroll
    for (int ks = 0; ks < 2; ++ks) {
        h8 raw = *(const h8*)(ar + ks * 32);
        int ch0 = ks * 32 + kg * 8;
        h8 a;
#pragma unroll
        for (int j = 0; j < 8; ++j) {
            float v = (float)raw[j] * scale[ch0 + j] + shift[ch0 + j];
            a[j] = (hf)fmaxf(v, 0.f);
        }
#pragma unroll
        for (int n = 0; n < 4; ++n) {
            h8 b = *(const h8*)(w2t + (n * 16 + r16) * HIDC + ks * 32 + kg * 8);
            acc[n] = __builtin_amdgcn_mfma_f32_16x16x32_f16(a, b, acc[n], 0, 0, 0);
        }
    }
#pragma unroll
    for (int j = 0; j < 4; ++j) {
        int nrow = nodeBase + wv * 16 + kg * 4 + j;
        if (nrow < NN) {
            float dv = dinv[nrow];
            size_t o = (size_t)nrow * HIDC + r16;
#pragma unroll
            for (int n = 0; n < 4; ++n)
                hp[o + n * 16] = (hf)(acc[n][j] * dv);
        }
    }
}

// ---------------- vectorized CSR gather + fused BN stats ----------------
// 16 lanes per row (h4 = 8B/lane), 4 edges in flight; dual accumulators.
// NOTE: every __shfl is executed by ALL 64 lanes (uniform control flow) --
// divergent shfl with an inactive source lane is undefined (R9 bug).
__global__ __launch_bounds__(256) void k_gather(
    const int* __restrict__ cursor, const int* __restrict__ srcSorted,
    const float* __restrict__ dinv, const hf* __restrict__ hp,
    hf* __restrict__ agg, float* gsum, float* gsq) {
    int tid = threadIdx.x;
    int wv = tid >> 6, lane = tid & 63;
    int sub = lane >> 4, l16 = lane & 15;
    int ch0 = l16 * 4;
    f4 rs = {0.f,0.f,0.f,0.f}, rq = {0.f,0.f,0.f,0.f};
    for (int n = blockIdx.x * 4 + wv; n < NN; n += 8192) {
        int beg = cursor[n], end = cursor[n + 1];
        f4 accA = {0.f,0.f,0.f,0.f}, accB = {0.f,0.f,0.f,0.f};
        if (sub == 0) {   // self-loop row
            h4 hv = *(const h4*)(hp + (size_t)n * HIDC + ch0);
#pragma unroll
            for (int j = 0; j < 4; ++j) accA[j] = (float)hv[j];
        }
        for (int base = beg; base < end; base += 64) {
            int m = end - base; if (m > 64) m = 64;
            int si = (base + lane < end) ? srcSorted[base + lane] : 0;
            int j = 0;
            for (; j + 8 <= m; j += 8) {          // uniform guard: all lanes active
                int sA = __shfl(si, j + sub);
                int sB = __shfl(si, j + 4 + sub);
                h4 a = *(const h4*)(hp + (size_t)sA * HIDC + ch0);
                h4 b = *(const h4*)(hp + (size_t)sB * HIDC + ch0);
#pragma unroll
                for (int q = 0; q < 4; ++q) { accA[q] += (float)a[q]; accB[q] += (float)b[q]; }
            }
            if (j + 4 <= m) {                      // uniform guard
                int sA = __shfl(si, j + sub);
                h4 a = *(const h4*)(hp + (size_t)sA * HIDC + ch0);
#pragma unroll
                for (int q = 0; q < 4; ++q) accA[q] += (float)a[q];
                j += 4;
            }
            int r = m - j;                         // 0..3
            // shfl hoisted OUT of the divergent branch: all lanes execute it,
            // source lane j + min(sub, r-1) is always < m when r > 0.
            int sA = __shfl(si, j + (sub < r ? sub : 0));
            if (sub < r) {
                h4 a = *(const h4*)(hp + (size_t)sA * HIDC + ch0);
#pragma unroll
                for (int q = 0; q < 4; ++q) accB[q] += (float)a[q];
            }
        }
        f4 acc;
#pragma unroll
        for (int j = 0; j < 4; ++j) {
            float v = accA[j] + accB[j];
            v += __shfl_xor(v, 16);
            v += __shfl_xor(v, 32);
            acc[j] = v;
        }
        if (sub == 0) {
            float dv = dinv[n];
            h4 o;
#pragma unroll
            for (int j = 0; j < 4; ++j) {
                float v = acc[j] * dv;
                o[j] = (hf)v;
                rs[j] += v; rq[j] += v * v;
            }
            *(h4*)(agg + (size_t)n * HIDC + ch0) = o;
        }
    }
    __shared__ float ssum[4][16][4], ssq[4][16][4];
    if (sub == 0) {
#pragma unroll
        for (int j = 0; j < 4; ++j) { ssum[wv][l16][j] = rs[j]; ssq[wv][l16][j] = rq[j]; }
    }
    __syncthreads();
    if (tid < 64) {
        int a = tid >> 2, bq = tid & 3;
        float s = ssum[0][a][bq] + ssum[1][a][bq] + ssum[2][a][bq] + ssum[3][a][bq];
        float q = ssq[0][a][bq] + ssq[1][a][bq] + ssq[2][a][bq] + ssq[3][a][bq];
        atomicAdd(&gsum[tid], s);
        atomicAdd(&gsq[tid], q);
    }
}

__global__ void k_bnfin(const float* __restrict__ gsum, const float* __restrict__ gsq,
                        const float* __restrict__ g, const float* __restrict__ be,
                        float* scale, float* shift) {
    int c = threadIdx.x;
    if (c < HIDC) {
        float mu = gsum[c] * (1.0f / NN);
        float var = gsq[c] * (1.0f / NN) - mu * mu;
        float inv = rsqrtf(var + EPSV);
        float sc = g[c] * inv;
        scale[c] = sc;
        shift[c] = be[c] - mu * sc;
    }
}

// ---------------- MLP head (fp16 agg input, BN+ReLU fused) ----------------
__global__ __launch_bounds__(256) void k_mlp(
    const hf* __restrict__ agg, const float* __restrict__ scale,
    const float* __restrict__ shift,
    const float* __restrict__ Wm1, const float* __restrict__ bm1,
    const float* __restrict__ Wm2, const float* __restrict__ bm2,
    const float* __restrict__ Wm3, const float* __restrict__ bm3,
    float* __restrict__ out) {
    int n = blockIdx.x * blockDim.x + threadIdx.x;
    if (n >= NN) return;
    float h[HIDC];
#pragma unroll
    for (int cq = 0; cq < 8; ++cq) {
        h8 v8 = *(const h8*)&agg[(size_t)n * HIDC + cq * 8];
#pragma unroll
        for (int j = 0; j < 8; ++j) {
            int c = cq * 8 + j;
            h[c] = fmaxf((float)v8[j] * scale[c] + shift[c], 0.0f);
        }
    }
    float a1[32];
#pragma unroll
    for (int j = 0; j < 32; ++j) {
        float acc = bm1[j];
#pragma unroll
        for (int c = 0; c < HIDC; ++c) acc += h[c] * Wm1[c * 32 + j];
        a1[j] = fmaxf(acc, 0.0f);
    }
    float a2[16];
#pragma unroll
    for (int j = 0; j < 16; ++j) {
        float acc = bm2[j];
#pragma unroll
        for (int c = 0; c < 32; ++c) acc += a1[c] * Wm2[c * 16 + j];
        a2[j] = fmaxf(acc, 0.0f);
    }
    float z = bm3[0];
#pragma unroll
    for (int c = 0; c < 16; ++c) z += a2[c] * Wm3[c];
    out[n] = 1.0f / (1.0f + expf(-z));
}

extern "C" void kernel_launch(void* const* d_in, const int* in_sizes, int n_in,
                              void* d_out, int out_size, void* d_ws, size_t ws_size,
                              hipStream_t stream) {
    const float* x   = (const float*)d_in[0];
    const int*   ei  = (const int*)d_in[1];
    const float* W1  = (const float*)d_in[2];
    // b1 (d_in[3]) cancels in BatchNorm
    const float* g1  = (const float*)d_in[4];
    const float* be1 = (const float*)d_in[5];
    const float* W2  = (const float*)d_in[6];
    // b2 (d_in[7]) cancels in BatchNorm
    const float* g2  = (const float*)d_in[8];
    const float* be2 = (const float*)d_in[9];
    const float* Wm1 = (const float*)d_in[10];
    const float* bm1 = (const float*)d_in[11];
    const float* Wm2 = (const float*)d_in[12];
    const float* bm2 = (const float*)d_in[13];
    const float* Wm3 = (const float*)d_in[14];
    const float* bm3 = (const float*)d_in[15];
    float* out = (float*)d_out;

    const int* srcI = ei;
    const int* dstI = ei + NE;

    int*   bucketTotal = (int*)d_ws;                    // 128
    int*   bucketStart = bucketTotal + 128;             // 128
    int*   bucketCur   = bucketStart + 128;             // 128
    int*   cursor      = bucketCur + 128;               // NN+4
    int*   srcSorted   = cursor + NN + 4;               // NE
    float* dinv        = (float*)(srcSorted + NE);      // NN
    hf*    w1t         = (hf*)(dinv + NN);              // 64*128
    hf*    w2t         = w1t + 64 * 128;                // 64*64
    hf*    hp          = w2t + 64 * 64;                 // NN*64 fp16
    hf*    agg         = hp + (size_t)NN * HIDC;        // NN*64 fp16
    float* stats       = (float*)(agg + (size_t)NN * HIDC);  // 512
    u64*   pairs       = (u64*)hp;                      // aliases hp (dead until gemm1)
    float *sum1 = stats,       *sq1 = stats + 64;
    float *sum2 = stats + 128, *sq2 = stats + 192;
    float *scale1 = stats + 256, *shift1 = stats + 320;
    float *scale2 = stats + 384, *shift2 = stats + 448;

    hipMemsetAsync(bucketTotal, 0, 128 * sizeof(int), stream);
    hipMemsetAsync(stats, 0, 256 * sizeof(float), stream);

    // CSR build (+ weight prep in block 0 of hist)
    k_histprep<<<(NE + CHUNK - 1) / CHUNK, 256, 0, stream>>>(dstI, bucketTotal, W1, W2, w1t, w2t);
    k_bscan<<<1, 128, 0, stream>>>(bucketTotal, bucketStart, bucketCur, cursor);
    k_partA<<<(NE + CHUNK - 1) / CHUNK, 256, 0, stream>>>(srcI, dstI, bucketCur, pairs);
    k_partB<<<NBUCK, 256, 0, stream>>>(bucketStart, pairs, srcSorted, cursor, dinv);

    // layer 1
    k_gemm1<<<(NN + 63) / 64, 256, 0, stream>>>(x, w1t, dinv, hp);
    k_gather<<<2048, 256, 0, stream>>>(cursor, srcSorted, dinv, hp, agg, sum1, sq1);
    k_bnfin<<<1, 64, 0, stream>>>(sum1, sq1, g1, be1, scale1, shift1);

    // layer 2
    k_gemm2<<<(NN + 63) / 64, 256, 0, stream>>>(agg, w2t, scale1, shift1, dinv, hp);
    k_gather<<<2048, 256, 0, stream>>>(cursor, srcSorted, dinv, hp, agg, sum2, sq2);
    k_bnfin<<<1, 64, 0, stream>>>(sum2, sq2, g2, be2, scale2, shift2);

    // MLP head
    k_mlp<<<(NN + 255) / 256, 256, 0, stream>>>(agg, scale2, shift2,
                                                Wm1, bm1, Wm2, bm2, Wm3, bm3, out);
}

// Round 11
// 345.491 us; speedup vs baseline: 1.0262x; 1.0262x over previous
//
#include <hip/hip_runtime.h>
#include <hip/hip_fp16.h>
#include <math.h>

#define NN 100000
#define NE 1200000
#define INC 128
#define HIDC 64
#define EPSV 1e-5f
#define NPB 1024                               // nodes per bucket
#define NBUCK ((NN + NPB - 1) / NPB)           // 98
#define CHUNK 8192                             // edges per partA/hist block

typedef float f4 __attribute__((ext_vector_type(4)));
typedef _Float16 hf;
typedef _Float16 h4 __attribute__((ext_vector_type(4)));
typedef _Float16 h8 __attribute__((ext_vector_type(8)));
typedef unsigned long long u64;

// ---- bucket histogram + (block 0) weight-transpose prep ----
__global__ __launch_bounds__(256) void k_histprep(
    const int* __restrict__ dst, int* bucketTotal,
    const float* __restrict__ W1, const float* __restrict__ W2,
    hf* __restrict__ w1t, hf* __restrict__ w2t) {
    __shared__ int hist[NBUCK];
    int t = threadIdx.x;
    if (blockIdx.x == 0) {
        for (int i = t; i < 64 * 128; i += 256) {
            int c = i >> 7, k = i & 127;
            w1t[i] = (hf)W1[k * 64 + c];
        }
        for (int i = t; i < 64 * 64; i += 256) {
            int c = i >> 6, k = i & 63;
            w2t[i] = (hf)W2[k * 64 + c];
        }
    }
    if (t < NBUCK) hist[t] = 0;
    __syncthreads();
    int e0 = blockIdx.x * CHUNK;
#pragma unroll
    for (int j = 0; j < CHUNK / 256; ++j) {
        int e = e0 + j * 256 + t;
        if (e < NE) atomicAdd(&hist[dst[e] >> 10], 1);
    }
    __syncthreads();
    if (t < NBUCK && hist[t]) atomicAdd(&bucketTotal[t], hist[t]);
}

// ---- scan bucket totals ----
__global__ void k_bscan(const int* __restrict__ bucketTotal,
                        int* bucketStart, int* bucketCur, int* cursor) {
    __shared__ int s[NBUCK];
    int t = threadIdx.x;
    if (t < NBUCK) s[t] = bucketTotal[t];
    __syncthreads();
    if (t == 0) {
        int acc = 0;
        for (int i = 0; i < NBUCK; ++i) { int v = s[i]; s[i] = acc; acc += v; }
    }
    __syncthreads();
    if (t < NBUCK) { bucketStart[t] = s[t]; bucketCur[t] = s[t]; }
    if (t == 0) { bucketStart[NBUCK] = NE; cursor[NN] = NE; }
}

// ---- pass A: partition (src,dst) pairs into bucket regions ----
__global__ __launch_bounds__(256) void k_partA(
    const int* __restrict__ src, const int* __restrict__ dst,
    int* bucketCur, u64* __restrict__ pairs) {
    __shared__ int hist[NBUCK], base[NBUCK];
    int t = threadIdx.x;
    if (t < NBUCK) hist[t] = 0;
    __syncthreads();
    int e0 = blockIdx.x * CHUNK;
    int dloc[32];
#pragma unroll
    for (int j = 0; j < 32; ++j) {
        int e = e0 + j * 256 + t;
        int d = (e < NE) ? dst[e] : -1;
        dloc[j] = d;
        if (d >= 0) atomicAdd(&hist[d >> 10], 1);
    }
    __syncthreads();
    if (t < NBUCK) base[t] = atomicAdd(&bucketCur[t], hist[t]);
    __syncthreads();
    if (t < NBUCK) hist[t] = 0;
    __syncthreads();
#pragma unroll
    for (int j = 0; j < 32; ++j) {
        int e = e0 + j * 256 + t;
        int d = dloc[j];
        if (d >= 0) {
            int b = d >> 10;
            int pos = base[b] + atomicAdd(&hist[b], 1);
            pairs[pos] = ((u64)(unsigned)d << 32) | (unsigned)src[e];
        }
    }
}

// ---- pass B: per-bucket counts -> cursor/dinv; local scatter ----
__global__ __launch_bounds__(256) void k_partB(
    const int* __restrict__ bucketStart, const u64* __restrict__ pairs,
    int* __restrict__ srcSorted, int* __restrict__ cursor, float* __restrict__ dinv) {
    __shared__ int cnt1024[NPB];
    __shared__ int off1024[NPB];
    __shared__ int part[256];
    int b = blockIdx.x, t = threadIdx.x;
    int nbase = b * NPB;
    int beg = bucketStart[b], end = bucketStart[b + 1];
    for (int i = t; i < NPB; i += 256) cnt1024[i] = 0;
    __syncthreads();
    for (int i = beg + t; i < end; i += 256)
        atomicAdd(&cnt1024[(int)(pairs[i] >> 32) - nbase], 1);
    __syncthreads();
    int c[4]; int s = 0;
#pragma unroll
    for (int j = 0; j < 4; ++j) { c[j] = cnt1024[t * 4 + j]; s += c[j]; }
    part[t] = s;
    __syncthreads();
    for (int off = 1; off < 256; off <<= 1) {
        int x = (t >= off) ? part[t - off] : 0;
        __syncthreads();
        part[t] += x;
        __syncthreads();
    }
    int run = part[t] - s;
#pragma unroll
    for (int j = 0; j < 4; ++j) {
        int node = nbase + t * 4 + j;
        if (node < NN) {
            cursor[node] = beg + run;
            off1024[t * 4 + j] = run;
            dinv[node] = rsqrtf((float)c[j] + 1.0f);
            run += c[j];
        }
    }
    __syncthreads();
    for (int i = beg + t; i < end; i += 256) {
        u64 p = pairs[i];
        int d = (int)(p >> 32);
        int pos = beg + atomicAdd(&off1024[d - nbase], 1);
        srcSorted[pos] = (int)(p & 0xffffffffu);
    }
}

// ---------------- layer-1 GEMM via MFMA ----------------
__global__ __launch_bounds__(256) void k_gemm1(
    const float* __restrict__ x, const hf* __restrict__ w1t,
    const float* __restrict__ dinv, hf* __restrict__ hp) {
    int wv = threadIdx.x >> 6, l = threadIdx.x & 63;
    int r16 = l & 15, kg = l >> 4;
    int nodeBase = blockIdx.x * 64;
    int row = nodeBase + wv * 16 + r16;
    int rowC = row < NN ? row : NN - 1;
    const float* xr = x + (size_t)rowC * INC + kg * 8;
    f4 acc[4] = {{0.f,0.f,0.f,0.f},{0.f,0.f,0.f,0.f},{0.f,0.f,0.f,0.f},{0.f,0.f,0.f,0.f}};
#pragma unroll
    for (int ks = 0; ks < 4; ++ks) {
        f4 alo = *(const f4*)(xr + ks * 32);
        f4 ahi = *(const f4*)(xr + ks * 32 + 4);
        h8 a;
#pragma unroll
        for (int j = 0; j < 4; ++j) { a[j] = (hf)alo[j]; a[4 + j] = (hf)ahi[j]; }
#pragma unroll
        for (int n = 0; n < 4; ++n) {
            h8 b = *(const h8*)(w1t + (n * 16 + r16) * INC + ks * 32 + kg * 8);
            acc[n] = __builtin_amdgcn_mfma_f32_16x16x32_f16(a, b, acc[n], 0, 0, 0);
        }
    }
#pragma unroll
    for (int j = 0; j < 4; ++j) {
        int nrow = nodeBase + wv * 16 + kg * 4 + j;
        if (nrow < NN) {
            float dv = dinv[nrow];
            size_t o = (size_t)nrow * HIDC + r16;
#pragma unroll
            for (int n = 0; n < 4; ++n)
                hp[o + n * 16] = (hf)(acc[n][j] * dv);
        }
    }
}

// ---------------- layer-2 GEMM via MFMA, BN+ReLU fused ----------------
__global__ __launch_bounds__(256) void k_gemm2(
    const hf* __restrict__ agg, const hf* __restrict__ w2t,
    const float* __restrict__ scale, const float* __restrict__ shift,
    const float* __restrict__ dinv, hf* __restrict__ hp) {
    int wv = threadIdx.x >> 6, l = threadIdx.x & 63;
    int r16 = l & 15, kg = l >> 4;
    int nodeBase = blockIdx.x * 64;
    int row = nodeBase + wv * 16 + r16;
    int rowC = row < NN ? row : NN - 1;
    const hf* ar = agg + (size_t)rowC * HIDC + kg * 8;
    f4 acc[4] = {{0.f,0.f,0.f,0.f},{0.f,0.f,0.f,0.f},{0.f,0.f,0.f,0.f},{0.f,0.f,0.f,0.f}};
#pragma unroll
    for (int ks = 0; ks < 2; ++ks) {
        h8 raw = *(const h8*)(ar + ks * 32);
        int ch0 = ks * 32 + kg * 8;
        h8 a;
#pragma unroll
        for (int j = 0; j < 8; ++j) {
            float v = (float)raw[j] * scale[ch0 + j] + shift[ch0 + j];
            a[j] = (hf)fmaxf(v, 0.f);
        }
#pragma unroll
        for (int n = 0; n < 4; ++n) {
            h8 b = *(const h8*)(w2t + (n * 16 + r16) * HIDC + ks * 32 + kg * 8);
            acc[n] = __builtin_amdgcn_mfma_f32_16x16x32_f16(a, b, acc[n], 0, 0, 0);
        }
    }
#pragma unroll
    for (int j = 0; j < 4; ++j) {
        int nrow = nodeBase + wv * 16 + kg * 4 + j;
        if (nrow < NN) {
            float dv = dinv[nrow];
            size_t o = (size_t)nrow * HIDC + r16;
#pragma unroll
            for (int n = 0; n < 4; ++n)
                hp[o + n * 16] = (hf)(acc[n][j] * dv);
        }
    }
}

// ---------------- CSR gather, lane = channel, 16-deep in-flight loads ----------------
// All __shfl executed by all 64 lanes (uniform control flow). Indices for
// j >= lim are clamped to lim-1 (duplicate loads -> L1 hits), accumulation
// predicated on wave-uniform j < lim. Fused BN stats (per-lane channel sums).
__global__ __launch_bounds__(256) void k_gather(
    const int* __restrict__ cursor, const int* __restrict__ srcSorted,
    const float* __restrict__ dinv, const hf* __restrict__ hp,
    hf* __restrict__ agg, float* gsum, float* gsq) {
    int tid = threadIdx.x;
    int wv = tid >> 6, lane = tid & 63;   // lane = channel
    float rs = 0.f, rq = 0.f;
    for (int n = blockIdx.x * 4 + wv; n < NN; n += 8192) {
        int beg = cursor[n], end = cursor[n + 1];
        float accA = (float)hp[(size_t)n * HIDC + lane];   // self-loop
        float accB = 0.f;
        for (int base = beg; base < end; base += 64) {
            int m = end - base; if (m > 64) m = 64;
            int si = (base + lane < end) ? srcSorted[base + lane] : 0;
            for (int j0 = 0; j0 < m; j0 += 16) {
                int lim = m - j0; if (lim > 16) lim = 16;   // >= 1
                float v[16];
#pragma unroll
                for (int j = 0; j < 16; ++j) {
                    int jj = (j < lim) ? j : (lim - 1);
                    int s = __shfl(si, j0 + jj);
                    v[j] = (float)hp[(size_t)s * HIDC + lane];
                }
#pragma unroll
                for (int j = 0; j < 16; j += 2) {
                    if (j < lim)     accA += v[j];
                    if (j + 1 < lim) accB += v[j + 1];
                }
            }
        }
        float o = (accA + accB) * dinv[n];
        agg[(size_t)n * HIDC + lane] = (hf)o;
        rs += o; rq += o * o;
    }
    __shared__ float ssum[4][64], ssq[4][64];
    ssum[wv][lane] = rs; ssq[wv][lane] = rq;
    __syncthreads();
    if (tid < 64) {
        float s = ssum[0][tid] + ssum[1][tid] + ssum[2][tid] + ssum[3][tid];
        float q = ssq[0][tid] + ssq[1][tid] + ssq[2][tid] + ssq[3][tid];
        atomicAdd(&gsum[tid], s);
        atomicAdd(&gsq[tid], q);
    }
}

__global__ void k_bnfin(const float* __restrict__ gsum, const float* __restrict__ gsq,
                        const float* __restrict__ g, const float* __restrict__ be,
                        float* scale, float* shift) {
    int c = threadIdx.x;
    if (c < HIDC) {
        float mu = gsum[c] * (1.0f / NN);
        float var = gsq[c] * (1.0f / NN) - mu * mu;
        float inv = rsqrtf(var + EPSV);
        float sc = g[c] * inv;
        scale[c] = sc;
        shift[c] = be[c] - mu * sc;
    }
}

// ---------------- MLP head (fp16 agg input, BN+ReLU fused) ----------------
__global__ __launch_bounds__(256) void k_mlp(
    const hf* __restrict__ agg, const float* __restrict__ scale,
    const float* __restrict__ shift,
    const float* __restrict__ Wm1, const float* __restrict__ bm1,
    const float* __restrict__ Wm2, const float* __restrict__ bm2,
    const float* __restrict__ Wm3, const float* __restrict__ bm3,
    float* __restrict__ out) {
    int n = blockIdx.x * blockDim.x + threadIdx.x;
    if (n >= NN) return;
    float h[HIDC];
#pragma unroll
    for (int cq = 0; cq < 8; ++cq) {
        h8 v8 = *(const h8*)&agg[(size_t)n * HIDC + cq * 8];
#pragma unroll
        for (int j = 0; j < 8; ++j) {
            int c = cq * 8 + j;
            h[c] = fmaxf((float)v8[j] * scale[c] + shift[c], 0.0f);
        }
    }
    float a1[32];
#pragma unroll
    for (int j = 0; j < 32; ++j) {
        float acc = bm1[j];
#pragma unroll
        for (int c = 0; c < HIDC; ++c) acc += h[c] * Wm1[c * 32 + j];
        a1[j] = fmaxf(acc, 0.0f);
    }
    float a2[16];
#pragma unroll
    for (int j = 0; j < 16; ++j) {
        float acc = bm2[j];
#pragma unroll
        for (int c = 0; c < 32; ++c) acc += a1[c] * Wm2[c * 16 + j];
        a2[j] = fmaxf(acc, 0.0f);
    }
    float z = bm3[0];
#pragma unroll
    for (int c = 0; c < 16; ++c) z += a2[c] * Wm3[c];
    out[n] = 1.0f / (1.0f + expf(-z));
}

extern "C" void kernel_launch(void* const* d_in, const int* in_sizes, int n_in,
                              void* d_out, int out_size, void* d_ws, size_t ws_size,
                              hipStream_t stream) {
    const float* x   = (const float*)d_in[0];
    const int*   ei  = (const int*)d_in[1];
    const float* W1  = (const float*)d_in[2];
    // b1 (d_in[3]) cancels in BatchNorm
    const float* g1  = (const float*)d_in[4];
    const float* be1 = (const float*)d_in[5];
    const float* W2  = (const float*)d_in[6];
    // b2 (d_in[7]) cancels in BatchNorm
    const float* g2  = (const float*)d_in[8];
    const float* be2 = (const float*)d_in[9];
    const float* Wm1 = (const float*)d_in[10];
    const float* bm1 = (const float*)d_in[11];
    const float* Wm2 = (const float*)d_in[12];
    const float* bm2 = (const float*)d_in[13];
    const float* Wm3 = (const float*)d_in[14];
    const float* bm3 = (const float*)d_in[15];
    float* out = (float*)d_out;

    const int* srcI = ei;
    const int* dstI = ei + NE;

    int*   bucketTotal = (int*)d_ws;                    // 128
    int*   bucketStart = bucketTotal + 128;             // 128
    int*   bucketCur   = bucketStart + 128;             // 128
    int*   cursor      = bucketCur + 128;               // NN+4
    int*   srcSorted   = cursor + NN + 4;               // NE
    float* dinv        = (float*)(srcSorted + NE);      // NN
    hf*    w1t         = (hf*)(dinv + NN);              // 64*128
    hf*    w2t         = w1t + 64 * 128;                // 64*64
    hf*    hp          = w2t + 64 * 64;                 // NN*64 fp16
    hf*    agg         = hp + (size_t)NN * HIDC;        // NN*64 fp16
    float* stats       = (float*)(agg + (size_t)NN * HIDC);  // 512
    u64*   pairs       = (u64*)hp;                      // aliases hp (dead until gemm1)
    float *sum1 = stats,       *sq1 = stats + 64;
    float *sum2 = stats + 128, *sq2 = stats + 192;
    float *scale1 = stats + 256, *shift1 = stats + 320;
    float *scale2 = stats + 384, *shift2 = stats + 448;

    hipMemsetAsync(bucketTotal, 0, 128 * sizeof(int), stream);
    hipMemsetAsync(stats, 0, 256 * sizeof(float), stream);

    // CSR build (+ weight prep in block 0 of hist)
    k_histprep<<<(NE + CHUNK - 1) / CHUNK, 256, 0, stream>>>(dstI, bucketTotal, W1, W2, w1t, w2t);
    k_bscan<<<1, 128, 0, stream>>>(bucketTotal, bucketStart, bucketCur, cursor);
    k_partA<<<(NE + CHUNK - 1) / CHUNK, 256, 0, stream>>>(srcI, dstI, bucketCur, pairs);
    k_partB<<<NBUCK, 256, 0, stream>>>(bucketStart, pairs, srcSorted, cursor, dinv);

    // layer 1
    k_gemm1<<<(NN + 63) / 64, 256, 0, stream>>>(x, w1t, dinv, hp);
    k_gather<<<2048, 256, 0, stream>>>(cursor, srcSorted, dinv, hp, agg, sum1, sq1);
    k_bnfin<<<1, 64, 0, stream>>>(sum1, sq1, g1, be1, scale1, shift1);

    // layer 2
    k_gemm2<<<(NN + 63) / 64, 256, 0, stream>>>(agg, w2t, scale1, shift1, dinv, hp);
    k_gather<<<2048, 256, 0, stream>>>(cursor, srcSorted, dinv, hp, agg, sum2, sq2);
    k_bnfin<<<1, 64, 0, stream>>>(sum2, sq2, g2, be2, scale2, shift2);

    // MLP head
    k_mlp<<<(NN + 255) / 256, 256, 0, stream>>>(agg, scale2, shift2,
                                                Wm1, bm1, Wm2, bm2, Wm3, bm3, out);
}

// Round 12
// 266.118 us; speedup vs baseline: 1.3322x; 1.2983x over previous
//
#include <hip/hip_runtime.h>
#include <hip/hip_fp16.h>
#include <math.h>

#define NN 100000
#define NE 1200000
#define INC 128
#define HIDC 64
#define EPSV 1e-5f
#define NPB 1024                               // nodes per bucket
#define NBUCK ((NN + NPB - 1) / NPB)           // 98
#define CAP 16384                              // edge capacity per bucket region
#define CHUNK 8192                             // edges per partA block

typedef float f4 __attribute__((ext_vector_type(4)));
typedef _Float16 hf;
typedef _Float16 h4 __attribute__((ext_vector_type(4)));
typedef _Float16 h8 __attribute__((ext_vector_type(8)));
typedef unsigned long long u64;

// ---- init: bucket cursors to fixed-capacity region starts; stats zero; weight prep ----
__global__ __launch_bounds__(256) void k_binit(
    int* bucketCur, float* stats,
    const float* __restrict__ W1, const float* __restrict__ W2,
    hf* __restrict__ w1t, hf* __restrict__ w2t) {
    int t = threadIdx.x;
    if (t < NBUCK) bucketCur[t] = t * CAP;
    if (t < 256) stats[t] = 0.f;
    for (int i = t; i < 64 * 128; i += 256) {
        int c = i >> 7, k = i & 127;
        w1t[i] = (hf)W1[k * 64 + c];
    }
    for (int i = t; i < 64 * 64; i += 256) {
        int c = i >> 6, k = i & 63;
        w2t[i] = (hf)W2[k * 64 + c];
    }
}

// ---- pass A: partition (src,dst) pairs into fixed-capacity bucket regions ----
__global__ __launch_bounds__(256) void k_partA(
    const int* __restrict__ src, const int* __restrict__ dst,
    int* bucketCur, u64* __restrict__ pairs) {
    __shared__ int hist[NBUCK], base[NBUCK];
    int t = threadIdx.x;
    if (t < NBUCK) hist[t] = 0;
    __syncthreads();
    int e0 = blockIdx.x * CHUNK;
    int dloc[32];
#pragma unroll
    for (int j = 0; j < 32; ++j) {
        int e = e0 + j * 256 + t;
        int d = (e < NE) ? dst[e] : -1;
        dloc[j] = d;
        if (d >= 0) atomicAdd(&hist[d >> 10], 1);
    }
    __syncthreads();
    if (t < NBUCK) base[t] = hist[t] ? atomicAdd(&bucketCur[t], hist[t]) : 0;
    __syncthreads();
    if (t < NBUCK) hist[t] = 0;
    __syncthreads();
#pragma unroll
    for (int j = 0; j < 32; ++j) {
        int e = e0 + j * 256 + t;
        int d = dloc[j];
        if (d >= 0) {
            int b = d >> 10;
            int pos = base[b] + atomicAdd(&hist[b], 1);
            pairs[pos] = ((u64)(unsigned)d << 32) | (unsigned)src[e];
        }
    }
}

// ---- pass B: per-bucket counts -> packed (beg,end) cursor, dinv; local scatter ----
__global__ __launch_bounds__(256) void k_partB(
    const int* __restrict__ bucketCur, const u64* __restrict__ pairs,
    int* __restrict__ srcSorted, u64* __restrict__ cursPacked, float* __restrict__ dinv) {
    __shared__ int cnt1024[NPB];
    __shared__ int off1024[NPB];
    __shared__ int part[256];
    int b = blockIdx.x, t = threadIdx.x;
    int nbase = b * NPB;
    int beg = b * CAP;
    int end = bucketCur[b];        // b*CAP + count_b after partA
    for (int i = t; i < NPB; i += 256) cnt1024[i] = 0;
    __syncthreads();
    for (int i = beg + t; i < end; i += 256)
        atomicAdd(&cnt1024[(int)(pairs[i] >> 32) - nbase], 1);
    __syncthreads();
    int c[4]; int s = 0;
#pragma unroll
    for (int j = 0; j < 4; ++j) { c[j] = cnt1024[t * 4 + j]; s += c[j]; }
    part[t] = s;
    __syncthreads();
    for (int off = 1; off < 256; off <<= 1) {
        int x = (t >= off) ? part[t - off] : 0;
        __syncthreads();
        part[t] += x;
        __syncthreads();
    }
    int run = part[t] - s;
#pragma unroll
    for (int j = 0; j < 4; ++j) {
        int node = nbase + t * 4 + j;
        if (node < NN) {
            int nb = beg + run;
            cursPacked[node] = ((u64)(unsigned)(nb + c[j]) << 32) | (unsigned)nb;
            off1024[t * 4 + j] = run;
            dinv[node] = rsqrtf((float)c[j] + 1.0f);
            run += c[j];
        }
    }
    __syncthreads();
    for (int i = beg + t; i < end; i += 256) {
        u64 p = pairs[i];
        int d = (int)(p >> 32);
        int pos = beg + atomicAdd(&off1024[d - nbase], 1);
        srcSorted[pos] = (int)(p & 0xffffffffu);
    }
}

// ---------------- layer-1 GEMM via MFMA ----------------
__global__ __launch_bounds__(256) void k_gemm1(
    const float* __restrict__ x, const hf* __restrict__ w1t,
    const float* __restrict__ dinv, hf* __restrict__ hp) {
    int wv = threadIdx.x >> 6, l = threadIdx.x & 63;
    int r16 = l & 15, kg = l >> 4;
    int nodeBase = blockIdx.x * 64;
    int row = nodeBase + wv * 16 + r16;
    int rowC = row < NN ? row : NN - 1;
    const float* xr = x + (size_t)rowC * INC + kg * 8;
    f4 acc[4] = {{0.f,0.f,0.f,0.f},{0.f,0.f,0.f,0.f},{0.f,0.f,0.f,0.f},{0.f,0.f,0.f,0.f}};
#pragma unroll
    for (int ks = 0; ks < 4; ++ks) {
        f4 alo = *(const f4*)(xr + ks * 32);
        f4 ahi = *(const f4*)(xr + ks * 32 + 4);
        h8 a;
#pragma unroll
        for (int j = 0; j < 4; ++j) { a[j] = (hf)alo[j]; a[4 + j] = (hf)ahi[j]; }
#pragma unroll
        for (int n = 0; n < 4; ++n) {
            h8 b = *(const h8*)(w1t + (n * 16 + r16) * INC + ks * 32 + kg * 8);
            acc[n] = __builtin_amdgcn_mfma_f32_16x16x32_f16(a, b, acc[n], 0, 0, 0);
        }
    }
#pragma unroll
    for (int j = 0; j < 4; ++j) {
        int nrow = nodeBase + wv * 16 + kg * 4 + j;
        if (nrow < NN) {
            float dv = dinv[nrow];
            size_t o = (size_t)nrow * HIDC + r16;
#pragma unroll
            for (int n = 0; n < 4; ++n)
                hp[o + n * 16] = (hf)(acc[n][j] * dv);
        }
    }
}

// ---------------- layer-2 GEMM via MFMA, BN+ReLU fused ----------------
__global__ __launch_bounds__(256) void k_gemm2(
    const hf* __restrict__ agg, const hf* __restrict__ w2t,
    const float* __restrict__ scale, const float* __restrict__ shift,
    const float* __restrict__ dinv, hf* __restrict__ hp) {
    int wv = threadIdx.x >> 6, l = threadIdx.x & 63;
    int r16 = l & 15, kg = l >> 4;
    int nodeBase = blockIdx.x * 64;
    int row = nodeBase + wv * 16 + r16;
    int rowC = row < NN ? row : NN - 1;
    const hf* ar = agg + (size_t)rowC * HIDC + kg * 8;
    f4 acc[4] = {{0.f,0.f,0.f,0.f},{0.f,0.f,0.f,0.f},{0.f,0.f,0.f,0.f},{0.f,0.f,0.f,0.f}};
#pragma unroll
    for (int ks = 0; ks < 2; ++ks) {
        h8 raw = *(const h8*)(ar + ks * 32);
        int ch0 = ks * 32 + kg * 8;
        h8 a;
#pragma unroll
        for (int j = 0; j < 8; ++j) {
            float v = (float)raw[j] * scale[ch0 + j] + shift[ch0 + j];
            a[j] = (hf)fmaxf(v, 0.f);
        }
#pragma unroll
        for (int n = 0; n < 4; ++n) {
            h8 b = *(const h8*)(w2t + (n * 16 + r16) * HIDC + ks * 32 + kg * 8);
            acc[n] = __builtin_amdgcn_mfma_f32_16x16x32_f16(a, b, acc[n], 0, 0, 0);
        }
    }
#pragma unroll
    for (int j = 0; j < 4; ++j) {
        int nrow = nodeBase + wv * 16 + kg * 4 + j;
        if (nrow < NN) {
            float dv = dinv[nrow];
            size_t o = (size_t)nrow * HIDC + r16;
#pragma unroll
            for (int n = 0; n < 4; ++n)
                hp[o + n * 16] = (hf)(acc[n][j] * dv);
        }
    }
}

// ---------------- CSR gather (R8-proven shape: one node per wave, lane = channel) ----------------
__global__ __launch_bounds__(256) void k_gather(
    const u64* __restrict__ cursPacked, const int* __restrict__ srcSorted,
    const float* __restrict__ dinv, const hf* __restrict__ hp,
    hf* __restrict__ agg) {
    int wid = threadIdx.x >> 6, lane = threadIdx.x & 63;
    int n = blockIdx.x * 4 + wid;
    if (n >= NN) return;
    u64 ce = cursPacked[n];
    int beg = (int)(ce & 0xffffffffu);
    int end = (int)(ce >> 32);
    float acc = (float)hp[(size_t)n * HIDC + lane];   // self-loop
    for (int base = beg; base < end; base += 64) {
        int m = end - base; if (m > 64) m = 64;
        int si = (base + lane < end) ? srcSorted[base + lane] : 0;
        int j = 0;
        for (; j + 8 <= m; j += 8) {
            int s0 = __shfl(si, j),     s1 = __shfl(si, j + 1);
            int s2 = __shfl(si, j + 2), s3 = __shfl(si, j + 3);
            int s4 = __shfl(si, j + 4), s5 = __shfl(si, j + 5);
            int s6 = __shfl(si, j + 6), s7 = __shfl(si, j + 7);
            float v0 = (float)hp[(size_t)s0 * HIDC + lane];
            float v1 = (float)hp[(size_t)s1 * HIDC + lane];
            float v2 = (float)hp[(size_t)s2 * HIDC + lane];
            float v3 = (float)hp[(size_t)s3 * HIDC + lane];
            float v4 = (float)hp[(size_t)s4 * HIDC + lane];
            float v5 = (float)hp[(size_t)s5 * HIDC + lane];
            float v6 = (float)hp[(size_t)s6 * HIDC + lane];
            float v7 = (float)hp[(size_t)s7 * HIDC + lane];
            acc += ((v0 + v1) + (v2 + v3)) + ((v4 + v5) + (v6 + v7));
        }
        for (; j + 2 <= m; j += 2) {
            int s0 = __shfl(si, j), s1 = __shfl(si, j + 1);
            float v0 = (float)hp[(size_t)s0 * HIDC + lane];
            float v1 = (float)hp[(size_t)s1 * HIDC + lane];
            acc += v0 + v1;
        }
        if (j < m) {
            int s = __shfl(si, j);
            acc += (float)hp[(size_t)s * HIDC + lane];
        }
    }
    agg[(size_t)n * HIDC + lane] = (hf)(dinv[n] * acc);
}

// ---------------- BN statistics (fp16 input, fp32 accumulate) ----------------
__global__ __launch_bounds__(256) void k_stats(
    const hf* __restrict__ agg, float* gsum, float* gsq) {
    __shared__ float ls[256], lq[256];
    int tid = threadIdx.x;
    int c = tid & 63, r = tid >> 6;
    float s = 0.0f, q = 0.0f;
    for (int n = blockIdx.x * 4 + r; n < NN; n += gridDim.x * 4) {
        float v = (float)agg[(size_t)n * HIDC + c];
        s += v; q += v * v;
    }
    ls[tid] = s; lq[tid] = q;
    __syncthreads();
    if (tid < 64) {
        s = ls[tid] + ls[tid + 64] + ls[tid + 128] + ls[tid + 192];
        q = lq[tid] + lq[tid + 64] + lq[tid + 128] + lq[tid + 192];
        atomicAdd(&gsum[c], s);
        atomicAdd(&gsq[c], q);
    }
}

__global__ void k_bnfin(const float* __restrict__ gsum, const float* __restrict__ gsq,
                        const float* __restrict__ g, const float* __restrict__ be,
                        float* scale, float* shift) {
    int c = threadIdx.x;
    if (c < HIDC) {
        float mu = gsum[c] * (1.0f / NN);
        float var = gsq[c] * (1.0f / NN) - mu * mu;
        float inv = rsqrtf(var + EPSV);
        float sc = g[c] * inv;
        scale[c] = sc;
        shift[c] = be[c] - mu * sc;
    }
}

// ---------------- MLP head (fp16 agg input, BN+ReLU fused) ----------------
__global__ __launch_bounds__(256) void k_mlp(
    const hf* __restrict__ agg, const float* __restrict__ scale,
    const float* __restrict__ shift,
    const float* __restrict__ Wm1, const float* __restrict__ bm1,
    const float* __restrict__ Wm2, const float* __restrict__ bm2,
    const float* __restrict__ Wm3, const float* __restrict__ bm3,
    float* __restrict__ out) {
    int n = blockIdx.x * blockDim.x + threadIdx.x;
    if (n >= NN) return;
    float h[HIDC];
#pragma unroll
    for (int cq = 0; cq < 8; ++cq) {
        h8 v8 = *(const h8*)&agg[(size_t)n * HIDC + cq * 8];
#pragma unroll
        for (int j = 0; j < 8; ++j) {
            int c = cq * 8 + j;
            h[c] = fmaxf((float)v8[j] * scale[c] + shift[c], 0.0f);
        }
    }
    float a1[32];
#pragma unroll
    for (int j = 0; j < 32; ++j) {
        float acc = bm1[j];
#pragma unroll
        for (int c = 0; c < HIDC; ++c) acc += h[c] * Wm1[c * 32 + j];
        a1[j] = fmaxf(acc, 0.0f);
    }
    float a2[16];
#pragma unroll
    for (int j = 0; j < 16; ++j) {
        float acc = bm2[j];
#pragma unroll
        for (int c = 0; c < 32; ++c) acc += a1[c] * Wm2[c * 16 + j];
        a2[j] = fmaxf(acc, 0.0f);
    }
    float z = bm3[0];
#pragma unroll
    for (int c = 0; c < 16; ++c) z += a2[c] * Wm3[c];
    out[n] = 1.0f / (1.0f + expf(-z));
}

extern "C" void kernel_launch(void* const* d_in, const int* in_sizes, int n_in,
                              void* d_out, int out_size, void* d_ws, size_t ws_size,
                              hipStream_t stream) {
    const float* x   = (const float*)d_in[0];
    const int*   ei  = (const int*)d_in[1];
    const float* W1  = (const float*)d_in[2];
    // b1 (d_in[3]) cancels in BatchNorm
    const float* g1  = (const float*)d_in[4];
    const float* be1 = (const float*)d_in[5];
    const float* W2  = (const float*)d_in[6];
    // b2 (d_in[7]) cancels in BatchNorm
    const float* g2  = (const float*)d_in[8];
    const float* be2 = (const float*)d_in[9];
    const float* Wm1 = (const float*)d_in[10];
    const float* bm1 = (const float*)d_in[11];
    const float* Wm2 = (const float*)d_in[12];
    const float* bm2 = (const float*)d_in[13];
    const float* Wm3 = (const float*)d_in[14];
    const float* bm3 = (const float*)d_in[15];
    float* out = (float*)d_out;

    const int* srcI = ei;
    const int* dstI = ei + NE;

    const size_t CAPT = (size_t)NBUCK * CAP;            // 1,605,632
    int*   bucketCur = (int*)d_ws;                      // 128
    float* stats     = (float*)(bucketCur + 128);       // 512
    u64*   cursPacked= (u64*)(stats + 512);             // NN u64 (8B-aligned: 128+512 ints = 2560B)
    int*   srcSorted = (int*)(cursPacked + NN);         // CAPT ints
    float* dinv      = (float*)(srcSorted + CAPT);      // NN
    hf*    w1t       = (hf*)(dinv + NN);                // 8192
    hf*    w2t       = w1t + 64 * 128;                  // 4096
    hf*    hp        = w2t + 64 * 64;                   // NN*64 fp16
    hf*    agg       = hp + (size_t)NN * HIDC;          // NN*64 fp16
    u64*   pairs     = (u64*)(agg + (size_t)NN * HIDC); // CAPT u64 (aligned: all prior sizes even)
    float *sum1 = stats,       *sq1 = stats + 64;
    float *sum2 = stats + 128, *sq2 = stats + 192;
    float *scale1 = stats + 256, *shift1 = stats + 320;
    float *scale2 = stats + 384, *shift2 = stats + 448;

    // CSR build: init -> partition -> per-bucket finalize
    k_binit<<<1, 256, 0, stream>>>(bucketCur, stats, W1, W2, w1t, w2t);
    k_partA<<<(NE + CHUNK - 1) / CHUNK, 256, 0, stream>>>(srcI, dstI, bucketCur, pairs);
    k_partB<<<NBUCK, 256, 0, stream>>>(bucketCur, pairs, srcSorted, cursPacked, dinv);

    // layer 1
    k_gemm1<<<(NN + 63) / 64, 256, 0, stream>>>(x, w1t, dinv, hp);
    k_gather<<<(NN + 3) / 4, 256, 0, stream>>>(cursPacked, srcSorted, dinv, hp, agg);
    k_stats<<<512, 256, 0, stream>>>(agg, sum1, sq1);
    k_bnfin<<<1, 64, 0, stream>>>(sum1, sq1, g1, be1, scale1, shift1);

    // layer 2
    k_gemm2<<<(NN + 63) / 64, 256, 0, stream>>>(agg, w2t, scale1, shift1, dinv, hp);
    k_gather<<<(NN + 3) / 4, 256, 0, stream>>>(cursPacked, srcSorted, dinv, hp, agg);
    k_stats<<<512, 256, 0, stream>>>(agg, sum2, sq2);
    k_bnfin<<<1, 64, 0, stream>>>(sum2, sq2, g2, be2, scale2, shift2);

    // MLP head
    k_mlp<<<(NN + 255) / 256, 256, 0, stream>>>(agg, scale2, shift2,
                                                Wm1, bm1, Wm2, bm2, Wm3, bm3, out);
}

// Round 13
// 253.693 us; speedup vs baseline: 1.3975x; 1.0490x over previous
//
#include <hip/hip_runtime.h>
#include <hip/hip_fp16.h>
#include <math.h>

#define NN 100000
#define NE 1200000
#define INC 128
#define HIDC 64
#define EPSV 1e-5f
#define NPB 1024                               // nodes per bucket
#define NBUCK ((NN + NPB - 1) / NPB)           // 98
#define PCAP 16384                             // pairs capacity per bucket (max ~12.9K)
#define SCAP 24576                             // padded srcSorted capacity per bucket
#define CHUNK 8192                             // edges per partA block

typedef float f4 __attribute__((ext_vector_type(4)));
typedef _Float16 hf;
typedef _Float16 h8 __attribute__((ext_vector_type(8)));
typedef unsigned int u32;
typedef unsigned long long u64;

// ---- init: bucket cursors, stats zero, weight prep, dummy hp row zero ----
__global__ __launch_bounds__(256) void k_binit(
    int* bucketCur, float* stats,
    const float* __restrict__ W1, const float* __restrict__ W2,
    hf* __restrict__ w1t, hf* __restrict__ w2t, hf* __restrict__ hp) {
    int t = threadIdx.x;
    if (t < NBUCK) bucketCur[t] = t * PCAP;
    if (t < 256) stats[t] = 0.f;
    if (t < HIDC) hp[(size_t)NN * HIDC + t] = (hf)0.f;   // dummy row for padded edges
    for (int i = t; i < 64 * 128; i += 256) {
        int c = i >> 7, k = i & 127;
        w1t[i] = (hf)W1[k * 64 + c];
    }
    for (int i = t; i < 64 * 64; i += 256) {
        int c = i >> 6, k = i & 63;
        w2t[i] = (hf)W2[k * 64 + c];
    }
}

// ---- pass A: partition edges into bucket regions as packed u32 (dloc<<17 | src) ----
__global__ __launch_bounds__(256) void k_partA(
    const int* __restrict__ src, const int* __restrict__ dst,
    int* bucketCur, u32* __restrict__ pairs) {
    __shared__ int hist[NBUCK], base[NBUCK];
    int t = threadIdx.x;
    if (t < NBUCK) hist[t] = 0;
    __syncthreads();
    int e0 = blockIdx.x * CHUNK;
    int dloc[32];
#pragma unroll
    for (int j = 0; j < 32; ++j) {
        int e = e0 + j * 256 + t;
        int d = (e < NE) ? dst[e] : -1;
        dloc[j] = d;
        if (d >= 0) atomicAdd(&hist[d >> 10], 1);
    }
    __syncthreads();
    if (t < NBUCK) base[t] = hist[t] ? atomicAdd(&bucketCur[t], hist[t]) : 0;
    __syncthreads();
    if (t < NBUCK) hist[t] = 0;
    __syncthreads();
#pragma unroll
    for (int j = 0; j < 32; ++j) {
        int e = e0 + j * 256 + t;
        int d = dloc[j];
        if (d >= 0) {
            int b = d >> 10;
            int pos = base[b] + atomicAdd(&hist[b], 1);
            pairs[pos] = ((u32)(d & 1023) << 17) | (u32)src[e];
        }
    }
}

// ---- pass B: per-bucket counts -> 16-padded segments; cursor/dinv; scatter + pad fill ----
__global__ __launch_bounds__(256) void k_partB(
    const int* __restrict__ bucketCur, const u32* __restrict__ pairs,
    int* __restrict__ srcSorted, u64* __restrict__ cursPacked, float* __restrict__ dinv) {
    __shared__ int cnt1024[NPB];
    __shared__ int off1024[NPB];
    __shared__ int part[256];
    __shared__ int totPad;
    int b = blockIdx.x, t = threadIdx.x;
    int nbase = b * NPB;
    int pbeg = b * PCAP;
    int pend = bucketCur[b];             // pbeg + real count
    int sbeg = b * SCAP;
    for (int i = t; i < NPB; i += 256) cnt1024[i] = 0;
    __syncthreads();
    for (int i = pbeg + t; i < pend; i += 256)
        atomicAdd(&cnt1024[pairs[i] >> 17], 1);
    __syncthreads();
    int c[4], pc[4]; int s = 0;
#pragma unroll
    for (int j = 0; j < 4; ++j) {
        c[j] = cnt1024[t * 4 + j];
        pc[j] = (c[j] + 15) & ~15;       // pad to multiple of 16
        s += pc[j];
    }
    part[t] = s;
    __syncthreads();
    for (int off = 1; off < 256; off <<= 1) {
        int x = (t >= off) ? part[t - off] : 0;
        __syncthreads();
        part[t] += x;
        __syncthreads();
    }
    if (t == 255) totPad = part[255];
    int run = part[t] - s;               // exclusive prefix of padded counts
#pragma unroll
    for (int j = 0; j < 4; ++j) {
        int node = nbase + t * 4 + j;
        if (node < NN) {
            int nb = sbeg + run;
            cursPacked[node] = ((u64)(u32)(nb + pc[j]) << 32) | (u32)nb;
            off1024[t * 4 + j] = run;
            dinv[node] = rsqrtf((float)c[j] + 1.0f);
            run += pc[j];
        }
    }
    __syncthreads();
    // init padded region with dummy index NN, then scatter real edges over it
    int tp = totPad;
    for (int i = t; i < tp; i += 256) srcSorted[sbeg + i] = NN;
    __syncthreads();
    for (int i = pbeg + t; i < pend; i += 256) {
        u32 p = pairs[i];
        int dl = (int)(p >> 17);
        int pos = sbeg + atomicAdd(&off1024[dl], 1);
        srcSorted[pos] = (int)(p & 0x1FFFFu);
    }
}

// ---------------- layer-1 GEMM via MFMA ----------------
__global__ __launch_bounds__(256) void k_gemm1(
    const float* __restrict__ x, const hf* __restrict__ w1t,
    const float* __restrict__ dinv, hf* __restrict__ hp) {
    int wv = threadIdx.x >> 6, l = threadIdx.x & 63;
    int r16 = l & 15, kg = l >> 4;
    int nodeBase = blockIdx.x * 64;
    int row = nodeBase + wv * 16 + r16;
    int rowC = row < NN ? row : NN - 1;
    const float* xr = x + (size_t)rowC * INC + kg * 8;
    f4 acc[4] = {{0.f,0.f,0.f,0.f},{0.f,0.f,0.f,0.f},{0.f,0.f,0.f,0.f},{0.f,0.f,0.f,0.f}};
#pragma unroll
    for (int ks = 0; ks < 4; ++ks) {
        f4 alo = *(const f4*)(xr + ks * 32);
        f4 ahi = *(const f4*)(xr + ks * 32 + 4);
        h8 a;
#pragma unroll
        for (int j = 0; j < 4; ++j) { a[j] = (hf)alo[j]; a[4 + j] = (hf)ahi[j]; }
#pragma unroll
        for (int n = 0; n < 4; ++n) {
            h8 b = *(const h8*)(w1t + (n * 16 + r16) * INC + ks * 32 + kg * 8);
            acc[n] = __builtin_amdgcn_mfma_f32_16x16x32_f16(a, b, acc[n], 0, 0, 0);
        }
    }
#pragma unroll
    for (int j = 0; j < 4; ++j) {
        int nrow = nodeBase + wv * 16 + kg * 4 + j;
        if (nrow < NN) {
            float dv = dinv[nrow];
            size_t o = (size_t)nrow * HIDC + r16;
#pragma unroll
            for (int n = 0; n < 4; ++n)
                hp[o + n * 16] = (hf)(acc[n][j] * dv);
        }
    }
}

// ---------------- layer-2 GEMM via MFMA, BN+ReLU fused ----------------
__global__ __launch_bounds__(256) void k_gemm2(
    const hf* __restrict__ agg, const hf* __restrict__ w2t,
    const float* __restrict__ scale, const float* __restrict__ shift,
    const float* __restrict__ dinv, hf* __restrict__ hp) {
    int wv = threadIdx.x >> 6, l = threadIdx.x & 63;
    int r16 = l & 15, kg = l >> 4;
    int nodeBase = blockIdx.x * 64;
    int row = nodeBase + wv * 16 + r16;
    int rowC = row < NN ? row : NN - 1;
    const hf* ar = agg + (size_t)rowC * HIDC + kg * 8;
    f4 acc[4] = {{0.f,0.f,0.f,0.f},{0.f,0.f,0.f,0.f},{0.f,0.f,0.f,0.f},{0.f,0.f,0.f,0.f}};
#pragma unroll
    for (int ks = 0; ks < 2; ++ks) {
        h8 raw = *(const h8*)(ar + ks * 32);
        int ch0 = ks * 32 + kg * 8;
        h8 a;
#pragma unroll
        for (int j = 0; j < 8; ++j) {
            float v = (float)raw[j] * scale[ch0 + j] + shift[ch0 + j];
            a[j] = (hf)fmaxf(v, 0.f);
        }
#pragma unroll
        for (int n = 0; n < 4; ++n) {
            h8 b = *(const h8*)(w2t + (n * 16 + r16) * HIDC + ks * 32 + kg * 8);
            acc[n] = __builtin_amdgcn_mfma_f32_16x16x32_f16(a, b, acc[n], 0, 0, 0);
        }
    }
#pragma unroll
    for (int j = 0; j < 4; ++j) {
        int nrow = nodeBase + wv * 16 + kg * 4 + j;
        if (nrow < NN) {
            float dv = dinv[nrow];
            size_t o = (size_t)nrow * HIDC + r16;
#pragma unroll
            for (int n = 0; n < 4; ++n)
                hp[o + n * 16] = (hf)(acc[n][j] * dv);
        }
    }
}

// ---------------- CSR gather: one node/wave, lane=channel, uniform 16-deep batches ----------------
// Edge segments are padded to multiples of 16 with dummy index NN (hp row NN = zeros),
// so the inner loop has NO tails and NO predication: 16 independent loads in flight.
__global__ __launch_bounds__(256) void k_gather(
    const u64* __restrict__ cursPacked, const int* __restrict__ srcSorted,
    const float* __restrict__ dinv, const hf* __restrict__ hp,
    hf* __restrict__ agg) {
    int wid = threadIdx.x >> 6, lane = threadIdx.x & 63;
    int n = blockIdx.x * 4 + wid;
    if (n >= NN) return;
    u64 ce = cursPacked[n];
    int beg = (int)(ce & 0xffffffffu);
    int end = (int)(ce >> 32);
    float accA = (float)hp[(size_t)n * HIDC + lane];   // self-loop
    float accB = 0.f;
    for (int base = beg; base < end; base += 64) {
        int m = end - base; if (m > 64) m = 64;        // multiple of 16
        int si = (base + lane < end) ? srcSorted[base + lane] : 0;
        for (int j = 0; j < m; j += 16) {
            int s0  = __shfl(si, j),      s1  = __shfl(si, j + 1);
            int s2  = __shfl(si, j + 2),  s3  = __shfl(si, j + 3);
            int s4  = __shfl(si, j + 4),  s5  = __shfl(si, j + 5);
            int s6  = __shfl(si, j + 6),  s7  = __shfl(si, j + 7);
            int s8  = __shfl(si, j + 8),  s9  = __shfl(si, j + 9);
            int s10 = __shfl(si, j + 10), s11 = __shfl(si, j + 11);
            int s12 = __shfl(si, j + 12), s13 = __shfl(si, j + 13);
            int s14 = __shfl(si, j + 14), s15 = __shfl(si, j + 15);
            float v0  = (float)hp[(size_t)s0  * HIDC + lane];
            float v1  = (float)hp[(size_t)s1  * HIDC + lane];
            float v2  = (float)hp[(size_t)s2  * HIDC + lane];
            float v3  = (float)hp[(size_t)s3  * HIDC + lane];
            float v4  = (float)hp[(size_t)s4  * HIDC + lane];
            float v5  = (float)hp[(size_t)s5  * HIDC + lane];
            float v6  = (float)hp[(size_t)s6  * HIDC + lane];
            float v7  = (float)hp[(size_t)s7  * HIDC + lane];
            float v8  = (float)hp[(size_t)s8  * HIDC + lane];
            float v9  = (float)hp[(size_t)s9  * HIDC + lane];
            float v10 = (float)hp[(size_t)s10 * HIDC + lane];
            float v11 = (float)hp[(size_t)s11 * HIDC + lane];
            float v12 = (float)hp[(size_t)s12 * HIDC + lane];
            float v13 = (float)hp[(size_t)s13 * HIDC + lane];
            float v14 = (float)hp[(size_t)s14 * HIDC + lane];
            float v15 = (float)hp[(size_t)s15 * HIDC + lane];
            accA += (((v0 + v1) + (v2 + v3)) + ((v4 + v5) + (v6 + v7)));
            accB += (((v8 + v9) + (v10 + v11)) + ((v12 + v13) + (v14 + v15)));
        }
    }
    agg[(size_t)n * HIDC + lane] = (hf)(dinv[n] * (accA + accB));
}

// ---------------- BN statistics (fp16 input, fp32 accumulate) ----------------
__global__ __launch_bounds__(256) void k_stats(
    const hf* __restrict__ agg, float* gsum, float* gsq) {
    __shared__ float ls[256], lq[256];
    int tid = threadIdx.x;
    int c = tid & 63, r = tid >> 6;
    float s = 0.0f, q = 0.0f;
    for (int n = blockIdx.x * 4 + r; n < NN; n += gridDim.x * 4) {
        float v = (float)agg[(size_t)n * HIDC + c];
        s += v; q += v * v;
    }
    ls[tid] = s; lq[tid] = q;
    __syncthreads();
    if (tid < 64) {
        s = ls[tid] + ls[tid + 64] + ls[tid + 128] + ls[tid + 192];
        q = lq[tid] + lq[tid + 64] + lq[tid + 128] + lq[tid + 192];
        atomicAdd(&gsum[c], s);
        atomicAdd(&gsq[c], q);
    }
}

__global__ void k_bnfin(const float* __restrict__ gsum, const float* __restrict__ gsq,
                        const float* __restrict__ g, const float* __restrict__ be,
                        float* scale, float* shift) {
    int c = threadIdx.x;
    if (c < HIDC) {
        float mu = gsum[c] * (1.0f / NN);
        float var = gsq[c] * (1.0f / NN) - mu * mu;
        float inv = rsqrtf(var + EPSV);
        float sc = g[c] * inv;
        scale[c] = sc;
        shift[c] = be[c] - mu * sc;
    }
}

// ---------------- MLP head (fp16 agg input, BN+ReLU fused) ----------------
__global__ __launch_bounds__(256) void k_mlp(
    const hf* __restrict__ agg, const float* __restrict__ scale,
    const float* __restrict__ shift,
    const float* __restrict__ Wm1, const float* __restrict__ bm1,
    const float* __restrict__ Wm2, const float* __restrict__ bm2,
    const float* __restrict__ Wm3, const float* __restrict__ bm3,
    float* __restrict__ out) {
    int n = blockIdx.x * blockDim.x + threadIdx.x;
    if (n >= NN) return;
    float h[HIDC];
#pragma unroll
    for (int cq = 0; cq < 8; ++cq) {
        h8 v8 = *(const h8*)&agg[(size_t)n * HIDC + cq * 8];
#pragma unroll
        for (int j = 0; j < 8; ++j) {
            int c = cq * 8 + j;
            h[c] = fmaxf((float)v8[j] * scale[c] + shift[c], 0.0f);
        }
    }
    float a1[32];
#pragma unroll
    for (int j = 0; j < 32; ++j) {
        float acc = bm1[j];
#pragma unroll
        for (int c = 0; c < HIDC; ++c) acc += h[c] * Wm1[c * 32 + j];
        a1[j] = fmaxf(acc, 0.0f);
    }
    float a2[16];
#pragma unroll
    for (int j = 0; j < 16; ++j) {
        float acc = bm2[j];
#pragma unroll
        for (int c = 0; c < 32; ++c) acc += a1[c] * Wm2[c * 16 + j];
        a2[j] = fmaxf(acc, 0.0f);
    }
    float z = bm3[0];
#pragma unroll
    for (int c = 0; c < 16; ++c) z += a2[c] * Wm3[c];
    out[n] = 1.0f / (1.0f + expf(-z));
}

extern "C" void kernel_launch(void* const* d_in, const int* in_sizes, int n_in,
                              void* d_out, int out_size, void* d_ws, size_t ws_size,
                              hipStream_t stream) {
    const float* x   = (const float*)d_in[0];
    const int*   ei  = (const int*)d_in[1];
    const float* W1  = (const float*)d_in[2];
    // b1 (d_in[3]) cancels in BatchNorm
    const float* g1  = (const float*)d_in[4];
    const float* be1 = (const float*)d_in[5];
    const float* W2  = (const float*)d_in[6];
    // b2 (d_in[7]) cancels in BatchNorm
    const float* g2  = (const float*)d_in[8];
    const float* be2 = (const float*)d_in[9];
    const float* Wm1 = (const float*)d_in[10];
    const float* bm1 = (const float*)d_in[11];
    const float* Wm2 = (const float*)d_in[12];
    const float* bm2 = (const float*)d_in[13];
    const float* Wm3 = (const float*)d_in[14];
    const float* bm3 = (const float*)d_in[15];
    float* out = (float*)d_out;

    const int* srcI = ei;
    const int* dstI = ei + NE;

    const size_t PCAPT = (size_t)NBUCK * PCAP;          // 1,605,632 u32
    const size_t SCAPT = (size_t)NBUCK * SCAP;          // 2,408,448 ints
    int*   bucketCur = (int*)d_ws;                      // 128
    float* stats     = (float*)(bucketCur + 128);       // 512
    u64*   cursPacked= (u64*)(stats + 512);             // NN u64 (8B-aligned)
    int*   srcSorted = (int*)(cursPacked + NN);         // SCAPT ints
    float* dinv      = (float*)(srcSorted + SCAPT);     // NN
    hf*    w1t       = (hf*)(dinv + NN);                // 8192
    hf*    w2t       = w1t + 64 * 128;                  // 4096
    hf*    hp        = w2t + 64 * 64;                   // (NN+1)*64 fp16 (+dummy row)
    hf*    agg       = hp + (size_t)(NN + 1) * HIDC;    // NN*64 fp16
    u32*   pairs     = (u32*)(agg + (size_t)NN * HIDC); // PCAPT u32
    float *sum1 = stats,       *sq1 = stats + 64;
    float *sum2 = stats + 128, *sq2 = stats + 192;
    float *scale1 = stats + 256, *shift1 = stats + 320;
    float *scale2 = stats + 384, *shift2 = stats + 448;

    // CSR build: init -> partition -> per-bucket finalize (16-padded segments)
    k_binit<<<1, 256, 0, stream>>>(bucketCur, stats, W1, W2, w1t, w2t, hp);
    k_partA<<<(NE + CHUNK - 1) / CHUNK, 256, 0, stream>>>(srcI, dstI, bucketCur, pairs);
    k_partB<<<NBUCK, 256, 0, stream>>>(bucketCur, pairs, srcSorted, cursPacked, dinv);

    // layer 1
    k_gemm1<<<(NN + 63) / 64, 256, 0, stream>>>(x, w1t, dinv, hp);
    k_gather<<<(NN + 3) / 4, 256, 0, stream>>>(cursPacked, srcSorted, dinv, hp, agg);
    k_stats<<<512, 256, 0, stream>>>(agg, sum1, sq1);
    k_bnfin<<<1, 64, 0, stream>>>(sum1, sq1, g1, be1, scale1, shift1);

    // layer 2
    k_gemm2<<<(NN + 63) / 64, 256, 0, stream>>>(agg, w2t, scale1, shift1, dinv, hp);
    k_gather<<<(NN + 3) / 4, 256, 0, stream>>>(cursPacked, srcSorted, dinv, hp, agg);
    k_stats<<<512, 256, 0, stream>>>(agg, sum2, sq2);
    k_bnfin<<<1, 64, 0, stream>>>(sum2, sq2, g2, be2, scale2, shift2);

    // MLP head
    k_mlp<<<(NN + 255) / 256, 256, 0, stream>>>(agg, scale2, shift2,
                                                Wm1, bm1, Wm2, bm2, Wm3, bm3, out);
}

// Round 14
// 251.543 us; speedup vs baseline: 1.4094x; 1.0085x over previous
//
#include <hip/hip_runtime.h>
#include <hip/hip_fp16.h>
#include <math.h>

#define NN 100000
#define NE 1200000
#define INC 128
#define HIDC 64
#define EPSV 1e-5f
#define NPB 1024                               // nodes per bucket
#define NBUCK ((NN + NPB - 1) / NPB)           // 98
#define PCAP 16384                             // pairs capacity per bucket (max ~12.9K)
#define SCAP 24576                             // padded srcSorted capacity per bucket
#define CHUNK 8192                             // edges per partA block

typedef float f4 __attribute__((ext_vector_type(4)));
typedef _Float16 hf;
typedef _Float16 h8 __attribute__((ext_vector_type(8)));
typedef unsigned int u32;
typedef unsigned long long u64;

// ---- init: bucket cursors, stats zero, weight prep, dummy hp row zero ----
__global__ __launch_bounds__(256) void k_binit(
    int* bucketCur, float* stats,
    const float* __restrict__ W1, const float* __restrict__ W2,
    hf* __restrict__ w1t, hf* __restrict__ w2t, hf* __restrict__ hp) {
    int t = threadIdx.x;
    if (t < NBUCK) bucketCur[t] = t * PCAP;
    if (t < 256) stats[t] = 0.f;
    if (t < HIDC) hp[(size_t)NN * HIDC + t] = (hf)0.f;   // dummy row for padded edges
    for (int i = t; i < 64 * 128; i += 256) {
        int c = i >> 7, k = i & 127;
        w1t[i] = (hf)W1[k * 64 + c];
    }
    for (int i = t; i < 64 * 64; i += 256) {
        int c = i >> 6, k = i & 63;
        w2t[i] = (hf)W2[k * 64 + c];
    }
}

// ---- pass A: partition edges into bucket regions as packed u32 (dloc<<17 | src) ----
__global__ __launch_bounds__(256) void k_partA(
    const int* __restrict__ src, const int* __restrict__ dst,
    int* bucketCur, u32* __restrict__ pairs) {
    __shared__ int hist[NBUCK], base[NBUCK];
    int t = threadIdx.x;
    if (t < NBUCK) hist[t] = 0;
    __syncthreads();
    int e0 = blockIdx.x * CHUNK;
    int dloc[32];
#pragma unroll
    for (int j = 0; j < 32; ++j) {
        int e = e0 + j * 256 + t;
        int d = (e < NE) ? dst[e] : -1;
        dloc[j] = d;
        if (d >= 0) atomicAdd(&hist[d >> 10], 1);
    }
    __syncthreads();
    if (t < NBUCK) base[t] = hist[t] ? atomicAdd(&bucketCur[t], hist[t]) : 0;
    __syncthreads();
    if (t < NBUCK) hist[t] = 0;
    __syncthreads();
#pragma unroll
    for (int j = 0; j < 32; ++j) {
        int e = e0 + j * 256 + t;
        int d = dloc[j];
        if (d >= 0) {
            int b = d >> 10;
            int pos = base[b] + atomicAdd(&hist[b], 1);
            pairs[pos] = ((u32)(d & 1023) << 17) | (u32)src[e];
        }
    }
}

// ---- pass B: per-bucket counts -> 16-padded segments; cursor/dinv; pad fill + scatter ----
__global__ __launch_bounds__(256) void k_partB(
    const int* __restrict__ bucketCur, const u32* __restrict__ pairs,
    int* __restrict__ srcSorted, u64* __restrict__ cursPacked, float* __restrict__ dinv) {
    __shared__ int cnt1024[NPB];
    __shared__ int off1024[NPB];
    __shared__ int part[256];
    int b = blockIdx.x, t = threadIdx.x;
    int nbase = b * NPB;
    int pbeg = b * PCAP;
    int pend = bucketCur[b];             // pbeg + real count
    int sbeg = b * SCAP;
    for (int i = t; i < NPB; i += 256) cnt1024[i] = 0;
    __syncthreads();
    for (int i = pbeg + t; i < pend; i += 256)
        atomicAdd(&cnt1024[pairs[i] >> 17], 1);
    __syncthreads();
    int c[4], pc[4]; int s = 0;
#pragma unroll
    for (int j = 0; j < 4; ++j) {
        c[j] = cnt1024[t * 4 + j];
        pc[j] = (c[j] + 15) & ~15;       // pad to multiple of 16
        s += pc[j];
    }
    part[t] = s;
    __syncthreads();
    for (int off = 1; off < 256; off <<= 1) {
        int x = (t >= off) ? part[t - off] : 0;
        __syncthreads();
        part[t] += x;
        __syncthreads();
    }
    int run = part[t] - s;               // exclusive prefix of padded counts
#pragma unroll
    for (int j = 0; j < 4; ++j) {
        int node = nbase + t * 4 + j;
        if (node < NN) {
            int nb = sbeg + run;
            cursPacked[node] = ((u64)(u32)(nb + pc[j]) << 32) | (u32)nb;
            off1024[t * 4 + j] = run;
            dinv[node] = rsqrtf((float)c[j] + 1.0f);
            for (int p = c[j]; p < pc[j]; ++p) srcSorted[nb + p] = NN;   // pad slots only
            run += pc[j];
        }
    }
    __syncthreads();
    for (int i = pbeg + t; i < pend; i += 256) {
        u32 p = pairs[i];
        int dl = (int)(p >> 17);
        int pos = sbeg + atomicAdd(&off1024[dl], 1);
        srcSorted[pos] = (int)(p & 0x1FFFFu);
    }
}

// ---------------- layer-1 GEMM via MFMA ----------------
__global__ __launch_bounds__(256) void k_gemm1(
    const float* __restrict__ x, const hf* __restrict__ w1t,
    const float* __restrict__ dinv, hf* __restrict__ hp) {
    int wv = threadIdx.x >> 6, l = threadIdx.x & 63;
    int r16 = l & 15, kg = l >> 4;
    int nodeBase = blockIdx.x * 64;
    int row = nodeBase + wv * 16 + r16;
    int rowC = row < NN ? row : NN - 1;
    const float* xr = x + (size_t)rowC * INC + kg * 8;
    f4 acc[4] = {{0.f,0.f,0.f,0.f},{0.f,0.f,0.f,0.f},{0.f,0.f,0.f,0.f},{0.f,0.f,0.f,0.f}};
#pragma unroll
    for (int ks = 0; ks < 4; ++ks) {
        f4 alo = *(const f4*)(xr + ks * 32);
        f4 ahi = *(const f4*)(xr + ks * 32 + 4);
        h8 a;
#pragma unroll
        for (int j = 0; j < 4; ++j) { a[j] = (hf)alo[j]; a[4 + j] = (hf)ahi[j]; }
#pragma unroll
        for (int n = 0; n < 4; ++n) {
            h8 b = *(const h8*)(w1t + (n * 16 + r16) * INC + ks * 32 + kg * 8);
            acc[n] = __builtin_amdgcn_mfma_f32_16x16x32_f16(a, b, acc[n], 0, 0, 0);
        }
    }
#pragma unroll
    for (int j = 0; j < 4; ++j) {
        int nrow = nodeBase + wv * 16 + kg * 4 + j;
        if (nrow < NN) {
            float dv = dinv[nrow];
            size_t o = (size_t)nrow * HIDC + r16;
#pragma unroll
            for (int n = 0; n < 4; ++n)
                hp[o + n * 16] = (hf)(acc[n][j] * dv);
        }
    }
}

// ---------------- layer-2 GEMM via MFMA, BN (from raw stats) + ReLU fused ----------------
__global__ __launch_bounds__(256) void k_gemm2(
    const hf* __restrict__ agg, const hf* __restrict__ w2t,
    const float* __restrict__ gsum, const float* __restrict__ gsq,
    const float* __restrict__ g, const float* __restrict__ be,
    const float* __restrict__ dinv, hf* __restrict__ hp) {
    __shared__ float ssc[HIDC], ssh[HIDC];
    int tid = threadIdx.x;
    if (tid < HIDC) {
        float mu = gsum[tid] * (1.0f / NN);
        float var = gsq[tid] * (1.0f / NN) - mu * mu;
        float inv = rsqrtf(var + EPSV);
        float sc = g[tid] * inv;
        ssc[tid] = sc;
        ssh[tid] = be[tid] - mu * sc;
    }
    __syncthreads();
    int wv = tid >> 6, l = tid & 63;
    int r16 = l & 15, kg = l >> 4;
    int nodeBase = blockIdx.x * 64;
    int row = nodeBase + wv * 16 + r16;
    int rowC = row < NN ? row : NN - 1;
    const hf* ar = agg + (size_t)rowC * HIDC + kg * 8;
    f4 acc[4] = {{0.f,0.f,0.f,0.f},{0.f,0.f,0.f,0.f},{0.f,0.f,0.f,0.f},{0.f,0.f,0.f,0.f}};
#pragma unroll
    for (int ks = 0; ks < 2; ++ks) {
        h8 raw = *(const h8*)(ar + ks * 32);
        int ch0 = ks * 32 + kg * 8;
        h8 a;
#pragma unroll
        for (int j = 0; j < 8; ++j) {
            float v = (float)raw[j] * ssc[ch0 + j] + ssh[ch0 + j];
            a[j] = (hf)fmaxf(v, 0.f);
        }
#pragma unroll
        for (int n = 0; n < 4; ++n) {
            h8 b = *(const h8*)(w2t + (n * 16 + r16) * HIDC + ks * 32 + kg * 8);
            acc[n] = __builtin_amdgcn_mfma_f32_16x16x32_f16(a, b, acc[n], 0, 0, 0);
        }
    }
#pragma unroll
    for (int j = 0; j < 4; ++j) {
        int nrow = nodeBase + wv * 16 + kg * 4 + j;
        if (nrow < NN) {
            float dv = dinv[nrow];
            size_t o = (size_t)nrow * HIDC + r16;
#pragma unroll
            for (int n = 0; n < 4; ++n)
                hp[o + n * 16] = (hf)(acc[n][j] * dv);
        }
    }
}

// ---------------- CSR gather: one node/wave, lane=channel, uniform 16-deep batches ----------------
__global__ __launch_bounds__(256) void k_gather(
    const u64* __restrict__ cursPacked, const int* __restrict__ srcSorted,
    const float* __restrict__ dinv, const hf* __restrict__ hp,
    hf* __restrict__ agg) {
    int wid = threadIdx.x >> 6, lane = threadIdx.x & 63;
    int n = blockIdx.x * 4 + wid;
    if (n >= NN) return;
    u64 ce = cursPacked[n];
    int beg = (int)(ce & 0xffffffffu);
    int end = (int)(ce >> 32);
    float accA = (float)hp[(size_t)n * HIDC + lane];   // self-loop
    float accB = 0.f;
    for (int base = beg; base < end; base += 64) {
        int m = end - base; if (m > 64) m = 64;        // multiple of 16
        int si = (base + lane < end) ? srcSorted[base + lane] : 0;
        for (int j = 0; j < m; j += 16) {
            int s0  = __shfl(si, j),      s1  = __shfl(si, j + 1);
            int s2  = __shfl(si, j + 2),  s3  = __shfl(si, j + 3);
            int s4  = __shfl(si, j + 4),  s5  = __shfl(si, j + 5);
            int s6  = __shfl(si, j + 6),  s7  = __shfl(si, j + 7);
            int s8  = __shfl(si, j + 8),  s9  = __shfl(si, j + 9);
            int s10 = __shfl(si, j + 10), s11 = __shfl(si, j + 11);
            int s12 = __shfl(si, j + 12), s13 = __shfl(si, j + 13);
            int s14 = __shfl(si, j + 14), s15 = __shfl(si, j + 15);
            float v0  = (float)hp[(size_t)s0  * HIDC + lane];
            float v1  = (float)hp[(size_t)s1  * HIDC + lane];
            float v2  = (float)hp[(size_t)s2  * HIDC + lane];
            float v3  = (float)hp[(size_t)s3  * HIDC + lane];
            float v4  = (float)hp[(size_t)s4  * HIDC + lane];
            float v5  = (float)hp[(size_t)s5  * HIDC + lane];
            float v6  = (float)hp[(size_t)s6  * HIDC + lane];
            float v7  = (float)hp[(size_t)s7  * HIDC + lane];
            float v8  = (float)hp[(size_t)s8  * HIDC + lane];
            float v9  = (float)hp[(size_t)s9  * HIDC + lane];
            float v10 = (float)hp[(size_t)s10 * HIDC + lane];
            float v11 = (float)hp[(size_t)s11 * HIDC + lane];
            float v12 = (float)hp[(size_t)s12 * HIDC + lane];
            float v13 = (float)hp[(size_t)s13 * HIDC + lane];
            float v14 = (float)hp[(size_t)s14 * HIDC + lane];
            float v15 = (float)hp[(size_t)s15 * HIDC + lane];
            accA += (((v0 + v1) + (v2 + v3)) + ((v4 + v5) + (v6 + v7)));
            accB += (((v8 + v9) + (v10 + v11)) + ((v12 + v13) + (v14 + v15)));
        }
    }
    agg[(size_t)n * HIDC + lane] = (hf)(dinv[n] * (accA + accB));
}

// ---------------- BN statistics (fp16 input, fp32 accumulate) ----------------
__global__ __launch_bounds__(256) void k_stats(
    const hf* __restrict__ agg, float* gsum, float* gsq) {
    __shared__ float ls[256], lq[256];
    int tid = threadIdx.x;
    int c = tid & 63, r = tid >> 6;
    float s = 0.0f, q = 0.0f;
    for (int n = blockIdx.x * 4 + r; n < NN; n += gridDim.x * 4) {
        float v = (float)agg[(size_t)n * HIDC + c];
        s += v; q += v * v;
    }
    ls[tid] = s; lq[tid] = q;
    __syncthreads();
    if (tid < 64) {
        s = ls[tid] + ls[tid + 64] + ls[tid + 128] + ls[tid + 192];
        q = lq[tid] + lq[tid + 64] + lq[tid + 128] + lq[tid + 192];
        atomicAdd(&gsum[c], s);
        atomicAdd(&gsq[c], q);
    }
}

// ---------------- MLP head, BN (from raw stats) + ReLU fused ----------------
__global__ __launch_bounds__(256) void k_mlp(
    const hf* __restrict__ agg,
    const float* __restrict__ gsum, const float* __restrict__ gsq,
    const float* __restrict__ g, const float* __restrict__ be,
    const float* __restrict__ Wm1, const float* __restrict__ bm1,
    const float* __restrict__ Wm2, const float* __restrict__ bm2,
    const float* __restrict__ Wm3, const float* __restrict__ bm3,
    float* __restrict__ out) {
    __shared__ float ssc[HIDC], ssh[HIDC];
    int tid = threadIdx.x;
    if (tid < HIDC) {
        float mu = gsum[tid] * (1.0f / NN);
        float var = gsq[tid] * (1.0f / NN) - mu * mu;
        float inv = rsqrtf(var + EPSV);
        float sc = g[tid] * inv;
        ssc[tid] = sc;
        ssh[tid] = be[tid] - mu * sc;
    }
    __syncthreads();
    int n = blockIdx.x * blockDim.x + tid;
    if (n >= NN) return;
    float h[HIDC];
#pragma unroll
    for (int cq = 0; cq < 8; ++cq) {
        h8 v8 = *(const h8*)&agg[(size_t)n * HIDC + cq * 8];
#pragma unroll
        for (int j = 0; j < 8; ++j) {
            int c = cq * 8 + j;
            h[c] = fmaxf((float)v8[j] * ssc[c] + ssh[c], 0.0f);
        }
    }
    float a1[32];
#pragma unroll
    for (int j = 0; j < 32; ++j) {
        float acc = bm1[j];
#pragma unroll
        for (int c = 0; c < HIDC; ++c) acc += h[c] * Wm1[c * 32 + j];
        a1[j] = fmaxf(acc, 0.0f);
    }
    float a2[16];
#pragma unroll
    for (int j = 0; j < 16; ++j) {
        float acc = bm2[j];
#pragma unroll
        for (int c = 0; c < 32; ++c) acc += a1[c] * Wm2[c * 16 + j];
        a2[j] = fmaxf(acc, 0.0f);
    }
    float z = bm3[0];
#pragma unroll
    for (int c = 0; c < 16; ++c) z += a2[c] * Wm3[c];
    out[n] = 1.0f / (1.0f + expf(-z));
}

extern "C" void kernel_launch(void* const* d_in, const int* in_sizes, int n_in,
                              void* d_out, int out_size, void* d_ws, size_t ws_size,
                              hipStream_t stream) {
    const float* x   = (const float*)d_in[0];
    const int*   ei  = (const int*)d_in[1];
    const float* W1  = (const float*)d_in[2];
    // b1 (d_in[3]) cancels in BatchNorm
    const float* g1  = (const float*)d_in[4];
    const float* be1 = (const float*)d_in[5];
    const float* W2  = (const float*)d_in[6];
    // b2 (d_in[7]) cancels in BatchNorm
    const float* g2  = (const float*)d_in[8];
    const float* be2 = (const float*)d_in[9];
    const float* Wm1 = (const float*)d_in[10];
    const float* bm1 = (const float*)d_in[11];
    const float* Wm2 = (const float*)d_in[12];
    const float* bm2 = (const float*)d_in[13];
    const float* Wm3 = (const float*)d_in[14];
    const float* bm3 = (const float*)d_in[15];
    float* out = (float*)d_out;

    const int* srcI = ei;
    const int* dstI = ei + NE;

    const size_t PCAPT = (size_t)NBUCK * PCAP;          // u32 pairs capacity
    const size_t SCAPT = (size_t)NBUCK * SCAP;          // padded srcSorted capacity
    int*   bucketCur = (int*)d_ws;                      // 128
    float* stats     = (float*)(bucketCur + 128);       // 512
    u64*   cursPacked= (u64*)(stats + 512);             // NN u64 (8B-aligned)
    int*   srcSorted = (int*)(cursPacked + NN);         // SCAPT ints
    float* dinv      = (float*)(srcSorted + SCAPT);     // NN
    hf*    w1t       = (hf*)(dinv + NN);                // 8192
    hf*    w2t       = w1t + 64 * 128;                  // 4096
    hf*    hp        = w2t + 64 * 64;                   // (NN+1)*64 fp16 (+dummy row)
    hf*    agg       = hp + (size_t)(NN + 1) * HIDC;    // NN*64 fp16
    u32*   pairs     = (u32*)(agg + (size_t)NN * HIDC); // PCAPT u32
    float *sum1 = stats,       *sq1 = stats + 64;
    float *sum2 = stats + 128, *sq2 = stats + 192;

    // CSR build: init -> partition -> per-bucket finalize (16-padded segments)
    k_binit<<<1, 256, 0, stream>>>(bucketCur, stats, W1, W2, w1t, w2t, hp);
    k_partA<<<(NE + CHUNK - 1) / CHUNK, 256, 0, stream>>>(srcI, dstI, bucketCur, pairs);
    k_partB<<<NBUCK, 256, 0, stream>>>(bucketCur, pairs, srcSorted, cursPacked, dinv);

    // layer 1
    k_gemm1<<<(NN + 63) / 64, 256, 0, stream>>>(x, w1t, dinv, hp);
    k_gather<<<(NN + 3) / 4, 256, 0, stream>>>(cursPacked, srcSorted, dinv, hp, agg);
    k_stats<<<512, 256, 0, stream>>>(agg, sum1, sq1);

    // layer 2 (BN folded into gemm2 from raw sums)
    k_gemm2<<<(NN + 63) / 64, 256, 0, stream>>>(agg, w2t, sum1, sq1, g1, be1, dinv, hp);
    k_gather<<<(NN + 3) / 4, 256, 0, stream>>>(cursPacked, srcSorted, dinv, hp, agg);
    k_stats<<<512, 256, 0, stream>>>(agg, sum2, sq2);

    // MLP head (BN folded in from raw sums)
    k_mlp<<<(NN + 255) / 256, 256, 0, stream>>>(agg, sum2, sq2, g2, be2,
                                                Wm1, bm1, Wm2, bm2, Wm3, bm3, out);
}

// Round 15
// 224.980 us; speedup vs baseline: 1.5758x; 1.1181x over previous
//
#include <hip/hip_runtime.h>
#include <hip/hip_fp16.h>
#include <math.h>

#define NN 100000
#define NE 1200000
#define INC 128
#define HIDC 64
#define EPSV 1e-5f
#define NPB 1024                               // nodes per bucket
#define NBUCK ((NN + NPB - 1) / NPB)           // 98
#define PCAP 16384                             // pairs capacity per bucket (max ~12.9K)
#define SCAP 24576                             // padded srcSorted capacity per bucket
#define CHUNK 8192                             // edges per partA block

typedef float f4 __attribute__((ext_vector_type(4)));
typedef _Float16 hf;
typedef _Float16 h8 __attribute__((ext_vector_type(8)));
typedef unsigned int u32;
typedef unsigned long long u64;

// ---- init: bucket cursors, stats zero, weight prep, dummy hp row zero ----
__global__ __launch_bounds__(256) void k_binit(
    int* bucketCur, float* stats,
    const float* __restrict__ W1, const float* __restrict__ W2,
    hf* __restrict__ w1t, hf* __restrict__ w2t, hf* __restrict__ hp) {
    int t = threadIdx.x;
    if (t < NBUCK) bucketCur[t] = t * PCAP;
    if (t < 256) stats[t] = 0.f;
    if (t < HIDC) hp[(size_t)NN * HIDC + t] = (hf)0.f;   // dummy row for padded edges
    for (int i = t; i < 64 * 128; i += 256) {
        int c = i >> 7, k = i & 127;
        w1t[i] = (hf)W1[k * 64 + c];
    }
    for (int i = t; i < 64 * 64; i += 256) {
        int c = i >> 6, k = i & 63;
        w2t[i] = (hf)W2[k * 64 + c];
    }
}

// ---- pass A: single-hist-pass partition; rank saved packed (d | rank<<17) ----
__global__ __launch_bounds__(256) void k_partA(
    const int* __restrict__ src, const int* __restrict__ dst,
    int* bucketCur, u32* __restrict__ pairs) {
    __shared__ int hist[NBUCK], base[NBUCK];
    int t = threadIdx.x;
    if (t < NBUCK) hist[t] = 0;
    __syncthreads();
    int e0 = blockIdx.x * CHUNK;
    u32 pk[32];
#pragma unroll
    for (int j = 0; j < 32; ++j) {
        int e = e0 + j * 256 + t;
        int d = (e < NE) ? dst[e] : -1;
        if (d >= 0) {
            int r = atomicAdd(&hist[d >> 10], 1);   // r < 8192, fits 15 bits
            pk[j] = (u32)d | ((u32)r << 17);
        } else {
            pk[j] = 0xFFFFFFFFu;                    // unreachable by valid (d,r)
        }
    }
    __syncthreads();
    if (t < NBUCK) base[t] = hist[t] ? atomicAdd(&bucketCur[t], hist[t]) : 0;
    __syncthreads();
#pragma unroll
    for (int j = 0; j < 32; ++j) {
        u32 p = pk[j];
        if (p != 0xFFFFFFFFu) {
            int d = (int)(p & 0x1FFFFu);
            int r = (int)(p >> 17);
            int e = e0 + j * 256 + t;
            pairs[base[d >> 10] + r] = ((u32)(d & 1023) << 17) | (u32)src[e];
        }
    }
}

// ---- pass B: per-bucket counts -> 16-padded segments; cursor/dinv; pad fill + scatter ----
__global__ __launch_bounds__(256) void k_partB(
    const int* __restrict__ bucketCur, const u32* __restrict__ pairs,
    int* __restrict__ srcSorted, u64* __restrict__ cursPacked, float* __restrict__ dinv) {
    __shared__ int cnt1024[NPB];
    __shared__ int off1024[NPB];
    __shared__ int part[256];
    int b = blockIdx.x, t = threadIdx.x;
    int nbase = b * NPB;
    int pbeg = b * PCAP;
    int pend = bucketCur[b];             // pbeg + real count
    int sbeg = b * SCAP;
    for (int i = t; i < NPB; i += 256) cnt1024[i] = 0;
    __syncthreads();
    for (int i = pbeg + t; i < pend; i += 256)
        atomicAdd(&cnt1024[pairs[i] >> 17], 1);
    __syncthreads();
    int c[4], pc[4]; int s = 0;
#pragma unroll
    for (int j = 0; j < 4; ++j) {
        c[j] = cnt1024[t * 4 + j];
        pc[j] = (c[j] + 15) & ~15;       // pad to multiple of 16
        s += pc[j];
    }
    part[t] = s;
    __syncthreads();
    for (int off = 1; off < 256; off <<= 1) {
        int x = (t >= off) ? part[t - off] : 0;
        __syncthreads();
        part[t] += x;
        __syncthreads();
    }
    int run = part[t] - s;               // exclusive prefix of padded counts
#pragma unroll
    for (int j = 0; j < 4; ++j) {
        int node = nbase + t * 4 + j;
        if (node < NN) {
            int nb = sbeg + run;
            cursPacked[node] = ((u64)(u32)(nb + pc[j]) << 32) | (u32)nb;
            off1024[t * 4 + j] = run;
            dinv[node] = rsqrtf((float)c[j] + 1.0f);
            for (int p = c[j]; p < pc[j]; ++p) srcSorted[nb + p] = NN;   // pad slots only
            run += pc[j];
        }
    }
    __syncthreads();
    for (int i = pbeg + t; i < pend; i += 256) {
        u32 p = pairs[i];
        int dl = (int)(p >> 17);
        int pos = sbeg + atomicAdd(&off1024[dl], 1);
        srcSorted[pos] = (int)(p & 0x1FFFFu);
    }
}

// ---------------- layer-1 GEMM via MFMA ----------------
__global__ __launch_bounds__(256) void k_gemm1(
    const float* __restrict__ x, const hf* __restrict__ w1t,
    const float* __restrict__ dinv, hf* __restrict__ hp) {
    int wv = threadIdx.x >> 6, l = threadIdx.x & 63;
    int r16 = l & 15, kg = l >> 4;
    int nodeBase = blockIdx.x * 64;
    int row = nodeBase + wv * 16 + r16;
    int rowC = row < NN ? row : NN - 1;
    const float* xr = x + (size_t)rowC * INC + kg * 8;
    f4 acc[4] = {{0.f,0.f,0.f,0.f},{0.f,0.f,0.f,0.f},{0.f,0.f,0.f,0.f},{0.f,0.f,0.f,0.f}};
#pragma unroll
    for (int ks = 0; ks < 4; ++ks) {
        f4 alo = *(const f4*)(xr + ks * 32);
        f4 ahi = *(const f4*)(xr + ks * 32 + 4);
        h8 a;
#pragma unroll
        for (int j = 0; j < 4; ++j) { a[j] = (hf)alo[j]; a[4 + j] = (hf)ahi[j]; }
#pragma unroll
        for (int n = 0; n < 4; ++n) {
            h8 b = *(const h8*)(w1t + (n * 16 + r16) * INC + ks * 32 + kg * 8);
            acc[n] = __builtin_amdgcn_mfma_f32_16x16x32_f16(a, b, acc[n], 0, 0, 0);
        }
    }
#pragma unroll
    for (int j = 0; j < 4; ++j) {
        int nrow = nodeBase + wv * 16 + kg * 4 + j;
        if (nrow < NN) {
            float dv = dinv[nrow];
            size_t o = (size_t)nrow * HIDC + r16;
#pragma unroll
            for (int n = 0; n < 4; ++n)
                hp[o + n * 16] = (hf)(acc[n][j] * dv);
        }
    }
}

// ---------------- layer-2 GEMM via MFMA, BN (from raw stats) + ReLU fused ----------------
__global__ __launch_bounds__(256) void k_gemm2(
    const hf* __restrict__ agg, const hf* __restrict__ w2t,
    const float* __restrict__ gsum, const float* __restrict__ gsq,
    const float* __restrict__ g, const float* __restrict__ be,
    const float* __restrict__ dinv, hf* __restrict__ hp) {
    __shared__ float ssc[HIDC], ssh[HIDC];
    int tid = threadIdx.x;
    if (tid < HIDC) {
        float mu = gsum[tid] * (1.0f / NN);
        float var = gsq[tid] * (1.0f / NN) - mu * mu;
        float inv = rsqrtf(var + EPSV);
        float sc = g[tid] * inv;
        ssc[tid] = sc;
        ssh[tid] = be[tid] - mu * sc;
    }
    __syncthreads();
    int wv = tid >> 6, l = tid & 63;
    int r16 = l & 15, kg = l >> 4;
    int nodeBase = blockIdx.x * 64;
    int row = nodeBase + wv * 16 + r16;
    int rowC = row < NN ? row : NN - 1;
    const hf* ar = agg + (size_t)rowC * HIDC + kg * 8;
    f4 acc[4] = {{0.f,0.f,0.f,0.f},{0.f,0.f,0.f,0.f},{0.f,0.f,0.f,0.f},{0.f,0.f,0.f,0.f}};
#pragma unroll
    for (int ks = 0; ks < 2; ++ks) {
        h8 raw = *(const h8*)(ar + ks * 32);
        int ch0 = ks * 32 + kg * 8;
        h8 a;
#pragma unroll
        for (int j = 0; j < 8; ++j) {
            float v = (float)raw[j] * ssc[ch0 + j] + ssh[ch0 + j];
            a[j] = (hf)fmaxf(v, 0.f);
        }
#pragma unroll
        for (int n = 0; n < 4; ++n) {
            h8 b = *(const h8*)(w2t + (n * 16 + r16) * HIDC + ks * 32 + kg * 8);
            acc[n] = __builtin_amdgcn_mfma_f32_16x16x32_f16(a, b, acc[n], 0, 0, 0);
        }
    }
#pragma unroll
    for (int j = 0; j < 4; ++j) {
        int nrow = nodeBase + wv * 16 + kg * 4 + j;
        if (nrow < NN) {
            float dv = dinv[nrow];
            size_t o = (size_t)nrow * HIDC + r16;
#pragma unroll
            for (int n = 0; n < 4; ++n)
                hp[o + n * 16] = (hf)(acc[n][j] * dv);
        }
    }
}

// ---------------- CSR gather: 2 nodes per wave, lane=channel, 16-deep batches x2 ----------------
// Wave handles nodes n0=blk*8+wid and n1=n0+4. All guards are wave-uniform
// (shfl-safe). Both nodes' loads issue before either accumulate -> up to 32
// independent row loads in flight per wave.
__global__ __launch_bounds__(256) void k_gather(
    const u64* __restrict__ cursPacked, const int* __restrict__ srcSorted,
    const float* __restrict__ dinv, const hf* __restrict__ hp,
    hf* __restrict__ agg) {
    int wid = threadIdx.x >> 6, lane = threadIdx.x & 63;
    int n0 = blockIdx.x * 8 + wid;      // NN = 100000 = 8 * 12500, always valid
    int n1 = n0 + 4;
    u64 ce0 = cursPacked[n0];
    u64 ce1 = cursPacked[n1];
    float dv0 = dinv[n0], dv1 = dinv[n1];
    int beg0 = (int)(ce0 & 0xffffffffu), end0 = (int)(ce0 >> 32);
    int beg1 = (int)(ce1 & 0xffffffffu), end1 = (int)(ce1 >> 32);
    float a0A = (float)hp[(size_t)n0 * HIDC + lane], a0B = 0.f;   // self-loops
    float a1A = (float)hp[(size_t)n1 * HIDC + lane], a1B = 0.f;
    int nb0 = (end0 - beg0) >> 4;
    int nb1 = (end1 - beg1) >> 4;
    int nbmax = nb0 > nb1 ? nb0 : nb1;
    int l16 = lane & 15;
    for (int i = 0; i < nbmax; ++i) {
        bool d0 = i < nb0, d1 = i < nb1;   // wave-uniform
        float v0[16], v1[16];
        int si0 = 0, si1 = 0;
        if (d0) si0 = srcSorted[beg0 + i * 16 + l16];
        if (d1) si1 = srcSorted[beg1 + i * 16 + l16];
        if (d0) {
#pragma unroll
            for (int j = 0; j < 16; ++j) {
                int s = __shfl(si0, j);
                v0[j] = (float)hp[(size_t)s * HIDC + lane];
            }
        }
        if (d1) {
#pragma unroll
            for (int j = 0; j < 16; ++j) {
                int s = __shfl(si1, j);
                v1[j] = (float)hp[(size_t)s * HIDC + lane];
            }
        }
        if (d0) {
            a0A += (((v0[0] + v0[1]) + (v0[2] + v0[3])) + ((v0[4] + v0[5]) + (v0[6] + v0[7])));
            a0B += (((v0[8] + v0[9]) + (v0[10] + v0[11])) + ((v0[12] + v0[13]) + (v0[14] + v0[15])));
        }
        if (d1) {
            a1A += (((v1[0] + v1[1]) + (v1[2] + v1[3])) + ((v1[4] + v1[5]) + (v1[6] + v1[7])));
            a1B += (((v1[8] + v1[9]) + (v1[10] + v1[11])) + ((v1[12] + v1[13]) + (v1[14] + v1[15])));
        }
    }
    agg[(size_t)n0 * HIDC + lane] = (hf)(dv0 * (a0A + a0B));
    agg[(size_t)n1 * HIDC + lane] = (hf)(dv1 * (a1A + a1B));
}

// ---------------- BN statistics: h8 vectorized loads, LDS transpose-reduce ----------------
__global__ __launch_bounds__(256) void k_stats(
    const hf* __restrict__ agg, float* gsum, float* gsq) {
    __shared__ float ls[256][8], lq[256][8];
    int tid = threadIdx.x;
    int cg = tid & 7, r = tid >> 3;         // 8 ch-groups x 32 rows per block-iter
    f4 sA = {0.f,0.f,0.f,0.f}, sB = sA, qA = sA, qB = sA;
    for (int n = blockIdx.x * 32 + r; n < NN; n += 512 * 32) {
        h8 v = *(const h8*)&agg[(size_t)n * HIDC + cg * 8];
#pragma unroll
        for (int j = 0; j < 4; ++j) {
            float a = (float)v[j], b = (float)v[4 + j];
            sA[j] += a; qA[j] += a * a;
            sB[j] += b; qB[j] += b * b;
        }
    }
#pragma unroll
    for (int j = 0; j < 4; ++j) {
        ls[tid][j] = sA[j]; ls[tid][4 + j] = sB[j];
        lq[tid][j] = qA[j]; lq[tid][4 + j] = qB[j];
    }
    __syncthreads();
    if (tid < 64) {
        int cgi = tid >> 3, ji = tid & 7;   // channel = cgi*8 + ji
        float s = 0.f, q = 0.f;
        for (int rr = 0; rr < 32; ++rr) {
            s += ls[cgi + rr * 8][ji];
            q += lq[cgi + rr * 8][ji];
        }
        atomicAdd(&gsum[tid], s);
        atomicAdd(&gsq[tid], q);
    }
}

// ---------------- MLP head, BN (from raw stats) + ReLU fused ----------------
__global__ __launch_bounds__(256) void k_mlp(
    const hf* __restrict__ agg,
    const float* __restrict__ gsum, const float* __restrict__ gsq,
    const float* __restrict__ g, const float* __restrict__ be,
    const float* __restrict__ Wm1, const float* __restrict__ bm1,
    const float* __restrict__ Wm2, const float* __restrict__ bm2,
    const float* __restrict__ Wm3, const float* __restrict__ bm3,
    float* __restrict__ out) {
    __shared__ float ssc[HIDC], ssh[HIDC];
    int tid = threadIdx.x;
    if (tid < HIDC) {
        float mu = gsum[tid] * (1.0f / NN);
        float var = gsq[tid] * (1.0f / NN) - mu * mu;
        float inv = rsqrtf(var + EPSV);
        float sc = g[tid] * inv;
        ssc[tid] = sc;
        ssh[tid] = be[tid] - mu * sc;
    }
    __syncthreads();
    int n = blockIdx.x * blockDim.x + tid;
    if (n >= NN) return;
    float h[HIDC];
#pragma unroll
    for (int cq = 0; cq < 8; ++cq) {
        h8 v8 = *(const h8*)&agg[(size_t)n * HIDC + cq * 8];
#pragma unroll
        for (int j = 0; j < 8; ++j) {
            int c = cq * 8 + j;
            h[c] = fmaxf((float)v8[j] * ssc[c] + ssh[c], 0.0f);
        }
    }
    float a1[32];
#pragma unroll
    for (int j = 0; j < 32; ++j) {
        float acc = bm1[j];
#pragma unroll
        for (int c = 0; c < HIDC; ++c) acc += h[c] * Wm1[c * 32 + j];
        a1[j] = fmaxf(acc, 0.0f);
    }
    float a2[16];
#pragma unroll
    for (int j = 0; j < 16; ++j) {
        float acc = bm2[j];
#pragma unroll
        for (int c = 0; c < 32; ++c) acc += a1[c] * Wm2[c * 16 + j];
        a2[j] = fmaxf(acc, 0.0f);
    }
    float z = bm3[0];
#pragma unroll
    for (int c = 0; c < 16; ++c) z += a2[c] * Wm3[c];
    out[n] = 1.0f / (1.0f + expf(-z));
}

extern "C" void kernel_launch(void* const* d_in, const int* in_sizes, int n_in,
                              void* d_out, int out_size, void* d_ws, size_t ws_size,
                              hipStream_t stream) {
    const float* x   = (const float*)d_in[0];
    const int*   ei  = (const int*)d_in[1];
    const float* W1  = (const float*)d_in[2];
    // b1 (d_in[3]) cancels in BatchNorm
    const float* g1  = (const float*)d_in[4];
    const float* be1 = (const float*)d_in[5];
    const float* W2  = (const float*)d_in[6];
    // b2 (d_in[7]) cancels in BatchNorm
    const float* g2  = (const float*)d_in[8];
    const float* be2 = (const float*)d_in[9];
    const float* Wm1 = (const float*)d_in[10];
    const float* bm1 = (const float*)d_in[11];
    const float* Wm2 = (const float*)d_in[12];
    const float* bm2 = (const float*)d_in[13];
    const float* Wm3 = (const float*)d_in[14];
    const float* bm3 = (const float*)d_in[15];
    float* out = (float*)d_out;

    const int* srcI = ei;
    const int* dstI = ei + NE;

    const size_t PCAPT = (size_t)NBUCK * PCAP;          // u32 pairs capacity
    const size_t SCAPT = (size_t)NBUCK * SCAP;          // padded srcSorted capacity
    int*   bucketCur = (int*)d_ws;                      // 128
    float* stats     = (float*)(bucketCur + 128);       // 512
    u64*   cursPacked= (u64*)(stats + 512);             // NN u64 (8B-aligned)
    int*   srcSorted = (int*)(cursPacked + NN);         // SCAPT ints
    float* dinv      = (float*)(srcSorted + SCAPT);     // NN
    hf*    w1t       = (hf*)(dinv + NN);                // 8192
    hf*    w2t       = w1t + 64 * 128;                  // 4096
    hf*    hp        = w2t + 64 * 64;                   // (NN+1)*64 fp16 (+dummy row)
    hf*    agg       = hp + (size_t)(NN + 1) * HIDC;    // NN*64 fp16
    u32*   pairs     = (u32*)(agg + (size_t)NN * HIDC); // PCAPT u32
    float *sum1 = stats,       *sq1 = stats + 64;
    float *sum2 = stats + 128, *sq2 = stats + 192;

    // CSR build: init -> partition (single-hist-pass) -> per-bucket finalize
    k_binit<<<1, 256, 0, stream>>>(bucketCur, stats, W1, W2, w1t, w2t, hp);
    k_partA<<<(NE + CHUNK - 1) / CHUNK, 256, 0, stream>>>(srcI, dstI, bucketCur, pairs);
    k_partB<<<NBUCK, 256, 0, stream>>>(bucketCur, pairs, srcSorted, cursPacked, dinv);

    // layer 1
    k_gemm1<<<(NN + 63) / 64, 256, 0, stream>>>(x, w1t, dinv, hp);
    k_gather<<<NN / 8, 256, 0, stream>>>(cursPacked, srcSorted, dinv, hp, agg);
    k_stats<<<512, 256, 0, stream>>>(agg, sum1, sq1);

    // layer 2 (BN folded into gemm2 from raw sums)
    k_gemm2<<<(NN + 63) / 64, 256, 0, stream>>>(agg, w2t, sum1, sq1, g1, be1, dinv, hp);
    k_gather<<<NN / 8, 256, 0, stream>>>(cursPacked, srcSorted, dinv, hp, agg);
    k_stats<<<512, 256, 0, stream>>>(agg, sum2, sq2);

    // MLP head (BN folded in from raw sums)
    k_mlp<<<(NN + 255) / 256, 256, 0, stream>>>(agg, sum2, sq2, g2, be2,
                                                Wm1, bm1, Wm2, bm2, Wm3, bm3, out);
}

// Round 16
// 222.825 us; speedup vs baseline: 1.5911x; 1.0097x over previous
//
#include <hip/hip_runtime.h>
#include <hip/hip_fp16.h>
#include <math.h>

#define NN 100000
#define NE 1200000
#define INC 128
#define HIDC 64
#define EPSV 1e-5f
#define NPB 1024                               // nodes per bucket
#define NBUCK ((NN + NPB - 1) / NPB)           // 98
#define PCAP 16384                             // pairs capacity per bucket (max ~12.9K)
#define SCAP 24576                             // padded srcSorted capacity per bucket
#define CHUNK 8192                             // edges per partA block

typedef float f4 __attribute__((ext_vector_type(4)));
typedef _Float16 hf;
typedef _Float16 h8 __attribute__((ext_vector_type(8)));
typedef unsigned int u32;
typedef unsigned long long u64;

// ---- init: bucket cursors, stats zero, weight prep, dummy hp row zero ----
__global__ __launch_bounds__(256) void k_binit(
    int* bucketCur, float* stats,
    const float* __restrict__ W1, const float* __restrict__ W2,
    hf* __restrict__ w1t, hf* __restrict__ w2t, hf* __restrict__ hp) {
    int t = threadIdx.x;
    if (t < NBUCK) bucketCur[t] = t * PCAP;
    if (t < 256) stats[t] = 0.f;
    if (t < HIDC) hp[(size_t)NN * HIDC + t] = (hf)0.f;   // dummy row for padded edges
    for (int i = t; i < 64 * 128; i += 256) {
        int c = i >> 7, k = i & 127;
        w1t[i] = (hf)W1[k * 64 + c];
    }
    for (int i = t; i < 64 * 64; i += 256) {
        int c = i >> 6, k = i & 63;
        w2t[i] = (hf)W2[k * 64 + c];
    }
}

// ---- pass A: single-hist-pass partition; rank saved packed (d | rank<<17) ----
__global__ __launch_bounds__(256) void k_partA(
    const int* __restrict__ src, const int* __restrict__ dst,
    int* bucketCur, u32* __restrict__ pairs) {
    __shared__ int hist[NBUCK], base[NBUCK];
    int t = threadIdx.x;
    if (t < NBUCK) hist[t] = 0;
    __syncthreads();
    int e0 = blockIdx.x * CHUNK;
    u32 pk[32];
#pragma unroll
    for (int j = 0; j < 32; ++j) {
        int e = e0 + j * 256 + t;
        int d = (e < NE) ? dst[e] : -1;
        if (d >= 0) {
            int r = atomicAdd(&hist[d >> 10], 1);   // r < 8192, fits 15 bits
            pk[j] = (u32)d | ((u32)r << 17);
        } else {
            pk[j] = 0xFFFFFFFFu;                    // unreachable by valid (d,r)
        }
    }
    __syncthreads();
    if (t < NBUCK) base[t] = hist[t] ? atomicAdd(&bucketCur[t], hist[t]) : 0;
    __syncthreads();
#pragma unroll
    for (int j = 0; j < 32; ++j) {
        u32 p = pk[j];
        if (p != 0xFFFFFFFFu) {
            int d = (int)(p & 0x1FFFFu);
            int r = (int)(p >> 17);
            int e = e0 + j * 256 + t;
            pairs[base[d >> 10] + r] = ((u32)(d & 1023) << 17) | (u32)src[e];
        }
    }
}

// ---- pass B: per-bucket counts -> 16-padded segments; cursor/dinv; pad fill + scatter ----
__global__ __launch_bounds__(256) void k_partB(
    const int* __restrict__ bucketCur, const u32* __restrict__ pairs,
    int* __restrict__ srcSorted, u64* __restrict__ cursPacked, float* __restrict__ dinv) {
    __shared__ int cnt1024[NPB];
    __shared__ int off1024[NPB];
    __shared__ int part[256];
    int b = blockIdx.x, t = threadIdx.x;
    int nbase = b * NPB;
    int pbeg = b * PCAP;
    int pend = bucketCur[b];             // pbeg + real count
    int sbeg = b * SCAP;
    for (int i = t; i < NPB; i += 256) cnt1024[i] = 0;
    __syncthreads();
    for (int i = pbeg + t; i < pend; i += 256)
        atomicAdd(&cnt1024[pairs[i] >> 17], 1);
    __syncthreads();
    int c[4], pc[4]; int s = 0;
#pragma unroll
    for (int j = 0; j < 4; ++j) {
        c[j] = cnt1024[t * 4 + j];
        pc[j] = (c[j] + 15) & ~15;       // pad to multiple of 16
        s += pc[j];
    }
    part[t] = s;
    __syncthreads();
    for (int off = 1; off < 256; off <<= 1) {
        int x = (t >= off) ? part[t - off] : 0;
        __syncthreads();
        part[t] += x;
        __syncthreads();
    }
    int run = part[t] - s;               // exclusive prefix of padded counts
#pragma unroll
    for (int j = 0; j < 4; ++j) {
        int node = nbase + t * 4 + j;
        if (node < NN) {
            int nb = sbeg + run;
            cursPacked[node] = ((u64)(u32)(nb + pc[j]) << 32) | (u32)nb;
            off1024[t * 4 + j] = run;
            dinv[node] = rsqrtf((float)c[j] + 1.0f);
            for (int p = c[j]; p < pc[j]; ++p) srcSorted[nb + p] = NN;   // pad slots only
            run += pc[j];
        }
    }
    __syncthreads();
    for (int i = pbeg + t; i < pend; i += 256) {
        u32 p = pairs[i];
        int dl = (int)(p >> 17);
        int pos = sbeg + atomicAdd(&off1024[dl], 1);
        srcSorted[pos] = (int)(p & 0x1FFFFu);
    }
}

// ---------------- layer-1 GEMM via MFMA ----------------
__global__ __launch_bounds__(256) void k_gemm1(
    const float* __restrict__ x, const hf* __restrict__ w1t,
    const float* __restrict__ dinv, hf* __restrict__ hp) {
    int wv = threadIdx.x >> 6, l = threadIdx.x & 63;
    int r16 = l & 15, kg = l >> 4;
    int nodeBase = blockIdx.x * 64;
    int row = nodeBase + wv * 16 + r16;
    int rowC = row < NN ? row : NN - 1;
    const float* xr = x + (size_t)rowC * INC + kg * 8;
    f4 acc[4] = {{0.f,0.f,0.f,0.f},{0.f,0.f,0.f,0.f},{0.f,0.f,0.f,0.f},{0.f,0.f,0.f,0.f}};
#pragma unroll
    for (int ks = 0; ks < 4; ++ks) {
        f4 alo = *(const f4*)(xr + ks * 32);
        f4 ahi = *(const f4*)(xr + ks * 32 + 4);
        h8 a;
#pragma unroll
        for (int j = 0; j < 4; ++j) { a[j] = (hf)alo[j]; a[4 + j] = (hf)ahi[j]; }
#pragma unroll
        for (int n = 0; n < 4; ++n) {
            h8 b = *(const h8*)(w1t + (n * 16 + r16) * INC + ks * 32 + kg * 8);
            acc[n] = __builtin_amdgcn_mfma_f32_16x16x32_f16(a, b, acc[n], 0, 0, 0);
        }
    }
#pragma unroll
    for (int j = 0; j < 4; ++j) {
        int nrow = nodeBase + wv * 16 + kg * 4 + j;
        if (nrow < NN) {
            float dv = dinv[nrow];
            size_t o = (size_t)nrow * HIDC + r16;
#pragma unroll
            for (int n = 0; n < 4; ++n)
                hp[o + n * 16] = (hf)(acc[n][j] * dv);
        }
    }
}

// ---------------- layer-2 GEMM via MFMA, BN (from raw stats) + ReLU fused ----------------
__global__ __launch_bounds__(256) void k_gemm2(
    const hf* __restrict__ agg, const hf* __restrict__ w2t,
    const float* __restrict__ gsum, const float* __restrict__ gsq,
    const float* __restrict__ g, const float* __restrict__ be,
    const float* __restrict__ dinv, hf* __restrict__ hp) {
    __shared__ float ssc[HIDC], ssh[HIDC];
    int tid = threadIdx.x;
    if (tid < HIDC) {
        float mu = gsum[tid] * (1.0f / NN);
        float var = gsq[tid] * (1.0f / NN) - mu * mu;
        float inv = rsqrtf(var + EPSV);
        float sc = g[tid] * inv;
        ssc[tid] = sc;
        ssh[tid] = be[tid] - mu * sc;
    }
    __syncthreads();
    int wv = tid >> 6, l = tid & 63;
    int r16 = l & 15, kg = l >> 4;
    int nodeBase = blockIdx.x * 64;
    int row = nodeBase + wv * 16 + r16;
    int rowC = row < NN ? row : NN - 1;
    const hf* ar = agg + (size_t)rowC * HIDC + kg * 8;
    f4 acc[4] = {{0.f,0.f,0.f,0.f},{0.f,0.f,0.f,0.f},{0.f,0.f,0.f,0.f},{0.f,0.f,0.f,0.f}};
#pragma unroll
    for (int ks = 0; ks < 2; ++ks) {
        h8 raw = *(const h8*)(ar + ks * 32);
        int ch0 = ks * 32 + kg * 8;
        h8 a;
#pragma unroll
        for (int j = 0; j < 8; ++j) {
            float v = (float)raw[j] * ssc[ch0 + j] + ssh[ch0 + j];
            a[j] = (hf)fmaxf(v, 0.f);
        }
#pragma unroll
        for (int n = 0; n < 4; ++n) {
            h8 b = *(const h8*)(w2t + (n * 16 + r16) * HIDC + ks * 32 + kg * 8);
            acc[n] = __builtin_amdgcn_mfma_f32_16x16x32_f16(a, b, acc[n], 0, 0, 0);
        }
    }
#pragma unroll
    for (int j = 0; j < 4; ++j) {
        int nrow = nodeBase + wv * 16 + kg * 4 + j;
        if (nrow < NN) {
            float dv = dinv[nrow];
            size_t o = (size_t)nrow * HIDC + r16;
#pragma unroll
            for (int n = 0; n < 4; ++n)
                hp[o + n * 16] = (hf)(acc[n][j] * dv);
        }
    }
}

// ---------------- CSR gather: 2 nodes/wave, SCALAR index loads, no shfl ----------------
// All segment bounds forced to SGPRs via readfirstlane (wave-uniform by
// construction). srcSorted indices load through the scalar pipe
// (s_load_dwordx16: 16 indices, one instruction); row loads are
// global_load_ushort with SGPR base. 32 row-loads in flight per wave.
__global__ __launch_bounds__(256) void k_gather(
    const u64* __restrict__ cursPacked, const int* __restrict__ srcSorted,
    const float* __restrict__ dinv, const hf* __restrict__ hp,
    hf* __restrict__ agg) {
    int wid = threadIdx.x >> 6, lane = threadIdx.x & 63;
    int n0 = blockIdx.x * 8 + wid;      // NN = 100000 = 8 * 12500, always valid
    int n1 = n0 + 4;
    u64 ce0 = cursPacked[n0];
    u64 ce1 = cursPacked[n1];
    float dv0 = dinv[n0], dv1 = dinv[n1];
    int beg0 = __builtin_amdgcn_readfirstlane((int)(ce0 & 0xffffffffu));
    int end0 = __builtin_amdgcn_readfirstlane((int)(ce0 >> 32));
    int beg1 = __builtin_amdgcn_readfirstlane((int)(ce1 & 0xffffffffu));
    int end1 = __builtin_amdgcn_readfirstlane((int)(ce1 >> 32));
    float a0A = (float)hp[(size_t)n0 * HIDC + lane], a0B = 0.f;   // self-loops
    float a1A = (float)hp[(size_t)n1 * HIDC + lane], a1B = 0.f;
    int nb0 = (end0 - beg0) >> 4;
    int nb1 = (end1 - beg1) >> 4;
    int nbmax = nb0 > nb1 ? nb0 : nb1;
    for (int i = 0; i < nbmax; ++i) {
        bool d0 = i < nb0, d1 = i < nb1;   // scalar (SGPR-derived) guards
        float v0[16], v1[16];
        if (d0) {
            const int* sp = srcSorted + beg0 + i * 16;   // fully uniform address
#pragma unroll
            for (int j = 0; j < 16; ++j) {
                int s = sp[j];                           // scalar load
                v0[j] = (float)hp[(size_t)s * HIDC + lane];
            }
        }
        if (d1) {
            const int* sp = srcSorted + beg1 + i * 16;
#pragma unroll
            for (int j = 0; j < 16; ++j) {
                int s = sp[j];
                v1[j] = (float)hp[(size_t)s * HIDC + lane];
            }
        }
        if (d0) {
            a0A += (((v0[0] + v0[1]) + (v0[2] + v0[3])) + ((v0[4] + v0[5]) + (v0[6] + v0[7])));
            a0B += (((v0[8] + v0[9]) + (v0[10] + v0[11])) + ((v0[12] + v0[13]) + (v0[14] + v0[15])));
        }
        if (d1) {
            a1A += (((v1[0] + v1[1]) + (v1[2] + v1[3])) + ((v1[4] + v1[5]) + (v1[6] + v1[7])));
            a1B += (((v1[8] + v1[9]) + (v1[10] + v1[11])) + ((v1[12] + v1[13]) + (v1[14] + v1[15])));
        }
    }
    agg[(size_t)n0 * HIDC + lane] = (hf)(dv0 * (a0A + a0B));
    agg[(size_t)n1 * HIDC + lane] = (hf)(dv1 * (a1A + a1B));
}

// ---------------- BN statistics: h8 vectorized loads, LDS transpose-reduce ----------------
__global__ __launch_bounds__(256) void k_stats(
    const hf* __restrict__ agg, float* gsum, float* gsq) {
    __shared__ float ls[256][8], lq[256][8];
    int tid = threadIdx.x;
    int cg = tid & 7, r = tid >> 3;         // 8 ch-groups x 32 rows per block-iter
    f4 sA = {0.f,0.f,0.f,0.f}, sB = sA, qA = sA, qB = sA;
    for (int n = blockIdx.x * 32 + r; n < NN; n += 512 * 32) {
        h8 v = *(const h8*)&agg[(size_t)n * HIDC + cg * 8];
#pragma unroll
        for (int j = 0; j < 4; ++j) {
            float a = (float)v[j], b = (float)v[4 + j];
            sA[j] += a; qA[j] += a * a;
            sB[j] += b; qB[j] += b * b;
        }
    }
#pragma unroll
    for (int j = 0; j < 4; ++j) {
        ls[tid][j] = sA[j]; ls[tid][4 + j] = sB[j];
        lq[tid][j] = qA[j]; lq[tid][4 + j] = qB[j];
    }
    __syncthreads();
    if (tid < 64) {
        int cgi = tid >> 3, ji = tid & 7;   // channel = cgi*8 + ji
        float s = 0.f, q = 0.f;
        for (int rr = 0; rr < 32; ++rr) {
            s += ls[cgi + rr * 8][ji];
            q += lq[cgi + rr * 8][ji];
        }
        atomicAdd(&gsum[tid], s);
        atomicAdd(&gsq[tid], q);
    }
}

// ---------------- MLP head, BN (from raw stats) + ReLU fused ----------------
__global__ __launch_bounds__(256) void k_mlp(
    const hf* __restrict__ agg,
    const float* __restrict__ gsum, const float* __restrict__ gsq,
    const float* __restrict__ g, const float* __restrict__ be,
    const float* __restrict__ Wm1, const float* __restrict__ bm1,
    const float* __restrict__ Wm2, const float* __restrict__ bm2,
    const float* __restrict__ Wm3, const float* __restrict__ bm3,
    float* __restrict__ out) {
    __shared__ float ssc[HIDC], ssh[HIDC];
    int tid = threadIdx.x;
    if (tid < HIDC) {
        float mu = gsum[tid] * (1.0f / NN);
        float var = gsq[tid] * (1.0f / NN) - mu * mu;
        float inv = rsqrtf(var + EPSV);
        float sc = g[tid] * inv;
        ssc[tid] = sc;
        ssh[tid] = be[tid] - mu * sc;
    }
    __syncthreads();
    int n = blockIdx.x * blockDim.x + tid;
    if (n >= NN) return;
    float h[HIDC];
#pragma unroll
    for (int cq = 0; cq < 8; ++cq) {
        h8 v8 = *(const h8*)&agg[(size_t)n * HIDC + cq * 8];
#pragma unroll
        for (int j = 0; j < 8; ++j) {
            int c = cq * 8 + j;
            h[c] = fmaxf((float)v8[j] * ssc[c] + ssh[c], 0.0f);
        }
    }
    float a1[32];
#pragma unroll
    for (int j = 0; j < 32; ++j) {
        float acc = bm1[j];
#pragma unroll
        for (int c = 0; c < HIDC; ++c) acc += h[c] * Wm1[c * 32 + j];
        a1[j] = fmaxf(acc, 0.0f);
    }
    float a2[16];
#pragma unroll
    for (int j = 0; j < 16; ++j) {
        float acc = bm2[j];
#pragma unroll
        for (int c = 0; c < 32; ++c) acc += a1[c] * Wm2[c * 16 + j];
        a2[j] = fmaxf(acc, 0.0f);
    }
    float z = bm3[0];
#pragma unroll
    for (int c = 0; c < 16; ++c) z += a2[c] * Wm3[c];
    out[n] = 1.0f / (1.0f + expf(-z));
}

extern "C" void kernel_launch(void* const* d_in, const int* in_sizes, int n_in,
                              void* d_out, int out_size, void* d_ws, size_t ws_size,
                              hipStream_t stream) {
    const float* x   = (const float*)d_in[0];
    const int*   ei  = (const int*)d_in[1];
    const float* W1  = (const float*)d_in[2];
    // b1 (d_in[3]) cancels in BatchNorm
    const float* g1  = (const float*)d_in[4];
    const float* be1 = (const float*)d_in[5];
    const float* W2  = (const float*)d_in[6];
    // b2 (d_in[7]) cancels in BatchNorm
    const float* g2  = (const float*)d_in[8];
    const float* be2 = (const float*)d_in[9];
    const float* Wm1 = (const float*)d_in[10];
    const float* bm1 = (const float*)d_in[11];
    const float* Wm2 = (const float*)d_in[12];
    const float* bm2 = (const float*)d_in[13];
    const float* Wm3 = (const float*)d_in[14];
    const float* bm3 = (const float*)d_in[15];
    float* out = (float*)d_out;

    const int* srcI = ei;
    const int* dstI = ei + NE;

    const size_t PCAPT = (size_t)NBUCK * PCAP;          // u32 pairs capacity
    const size_t SCAPT = (size_t)NBUCK * SCAP;          // padded srcSorted capacity
    int*   bucketCur = (int*)d_ws;                      // 128
    float* stats     = (float*)(bucketCur + 128);       // 512
    u64*   cursPacked= (u64*)(stats + 512);             // NN u64 (8B-aligned)
    int*   srcSorted = (int*)(cursPacked + NN);         // SCAPT ints
    float* dinv      = (float*)(srcSorted + SCAPT);     // NN
    hf*    w1t       = (hf*)(dinv + NN);                // 8192
    hf*    w2t       = w1t + 64 * 128;                  // 4096
    hf*    hp        = w2t + 64 * 64;                   // (NN+1)*64 fp16 (+dummy row)
    hf*    agg       = hp + (size_t)(NN + 1) * HIDC;    // NN*64 fp16
    u32*   pairs     = (u32*)(agg + (size_t)NN * HIDC); // PCAPT u32
    float *sum1 = stats,       *sq1 = stats + 64;
    float *sum2 = stats + 128, *sq2 = stats + 192;

    // CSR build: init -> partition (single-hist-pass) -> per-bucket finalize
    k_binit<<<1, 256, 0, stream>>>(bucketCur, stats, W1, W2, w1t, w2t, hp);
    k_partA<<<(NE + CHUNK - 1) / CHUNK, 256, 0, stream>>>(srcI, dstI, bucketCur, pairs);
    k_partB<<<NBUCK, 256, 0, stream>>>(bucketCur, pairs, srcSorted, cursPacked, dinv);

    // layer 1
    k_gemm1<<<(NN + 63) / 64, 256, 0, stream>>>(x, w1t, dinv, hp);
    k_gather<<<NN / 8, 256, 0, stream>>>(cursPacked, srcSorted, dinv, hp, agg);
    k_stats<<<512, 256, 0, stream>>>(agg, sum1, sq1);

    // layer 2 (BN folded into gemm2 from raw sums)
    k_gemm2<<<(NN + 63) / 64, 256, 0, stream>>>(agg, w2t, sum1, sq1, g1, be1, dinv, hp);
    k_gather<<<NN / 8, 256, 0, stream>>>(cursPacked, srcSorted, dinv, hp, agg);
    k_stats<<<512, 256, 0, stream>>>(agg, sum2, sq2);

    // MLP head (BN folded in from raw sums)
    k_mlp<<<(NN + 255) / 256, 256, 0, stream>>>(agg, sum2, sq2, g2, be2,
                                                Wm1, bm1, Wm2, bm2, Wm3, bm3, out);
}